// Round 6
// baseline (455.449 us; speedup 1.0000x reference)
//
#include <hip/hip_runtime.h>
#include <stdint.h>

#define NBOX 2000000
#define NCLS 10
#define KPRE 4096
#define KPOST 500
#define NSEG 64
#define SEGC 4096   // cand per-segment cap
#define SEG2 1024   // sel per-segment cap
#define PSEG 2048   // pairs per-segment cap
#define LCAP 16384  // LDS pair cache (64 KB)
#define CSTR 16     // counter stride in u32 (one 64B cacheline per counter)

// ---- workspace layout (bytes) ----
#define OFF_KEYS   ((size_t)0)                               // NBOX*4 = 8 MB (u32 ord; idx implicit)
#define OFF_CAND   ((size_t)8000000)
#define OFF_SEL    (OFF_CAND  + (size_t)NSEG * SEGC * 8)
#define OFF_SKEYS  (OFF_SEL   + (size_t)NSEG * SEG2 * 8)
#define OFF_PAIRS  (OFF_SKEYS + (size_t)KPRE * 8)
#define OFF_VMASK  (OFF_PAIRS + (size_t)NSEG * PSEG * 4)
#define OFF_HIST   (OFF_VMASK + (size_t)64 * 8)
#define OFF_CNTS   (OFF_HIST  + (size_t)768 * 4)             // 3*64 counters, 64B stride
#define OFF_STATE  (OFF_CNTS  + (size_t)3 * NSEG * CSTR * 4)
#define OFF_ARR    (OFF_STATE + (size_t)64)
#define OFF_LAB    (OFF_ARR   + (size_t)KPRE * 24)           // NBOX u8 labels

struct NmsState {
  unsigned long long pivot;
};

__device__ __forceinline__ uint32_t f2ord(float f) {
  uint32_t b = __float_as_uint(f);
  return (b & 0x80000000u) ? ~b : (b | 0x80000000u);
}
__device__ __forceinline__ float ord2f(uint32_t ord) {
  uint32_t b = (ord & 0x80000000u) ? (ord ^ 0x80000000u) : ~ord;
  return __uint_as_float(b);
}

// find bucket of the need-th smallest in a 256-bin histogram; *nd = rank within bucket
__device__ uint32_t scan256(const uint32_t* __restrict__ h, uint32_t need, uint32_t* nd) {
  uint32_t cum = 0;
  for (int i = 0; i < 256; ++i) {
    uint32_t c = h[i];
    if (cum + c >= need) { *nd = need - cum; return (uint32_t)i; }
    cum += c;
  }
  *nd = 1; return 255u;  // unreachable on valid input
}

// wave-aggregated compaction (u64 payload): one atomic per wave
__device__ __forceinline__ void wave_compact(bool take, unsigned long long key,
                                             uint32_t* counter, unsigned long long* buf,
                                             uint32_t cap) {
  unsigned long long mm = __ballot(take);
  if (take) {
    int lane = threadIdx.x & 63;
    unsigned long long lt = (lane == 0) ? 0ull : (~0ull >> (64 - lane));
    int rank = __builtin_popcountll(mm & lt);
    int leader = __builtin_ctzll(mm);
    uint32_t base = 0;
    if (rank == 0) base = atomicAdd(counter, (uint32_t)__builtin_popcountll(mm));
    base = __shfl(base, leader);
    uint32_t pos = base + (uint32_t)rank;
    if (pos < cap) buf[pos] = key;
  }
}

// wave-aggregated compaction (u32 payload)
__device__ __forceinline__ void wave_compact32(bool take, uint32_t key,
                                               uint32_t* counter, uint32_t* buf,
                                               uint32_t cap) {
  unsigned long long mm = __ballot(take);
  if (take) {
    int lane = threadIdx.x & 63;
    unsigned long long lt = (lane == 0) ? 0ull : (~0ull >> (64 - lane));
    int rank = __builtin_popcountll(mm & lt);
    int leader = __builtin_ctzll(mm);
    uint32_t base = 0;
    if (rank == 0) base = atomicAdd(counter, (uint32_t)__builtin_popcountll(mm));
    base = __shfl(base, leader);
    uint32_t pos = base + (uint32_t)rank;
    if (pos < cap) buf[pos] = key;
  }
}

// ---------------- kernels ----------------

__global__ void k_zero(uint32_t* hist, NmsState* st, unsigned long long* vmask,
                       uint32_t* cnts) {
  int t = threadIdx.x;
  for (int i = t; i < 768; i += blockDim.x) hist[i] = 0;
  for (int i = t; i < 3 * NSEG * CSTR; i += blockDim.x) cnts[i] = 0;
  if (t < 64) vmask[t] = 0;
  if (t == 0) st->pivot = 0;
}

// scores (max over classes) -> u32 ord keys + per-box argmax label + byte0 histogram
__global__ void k_score(const float* __restrict__ cls, uint32_t* __restrict__ keys,
                        uint8_t* __restrict__ labs, uint32_t* __restrict__ hist0) {
  __shared__ uint32_t lh[256];
  for (int i = threadIdx.x; i < 256; i += blockDim.x) lh[i] = 0;
  __syncthreads();
  const int nvec = NBOX / 4;
  for (int v = blockIdx.x * blockDim.x + threadIdx.x; v < nvec; v += gridDim.x * blockDim.x) {
    float4 m = reinterpret_cast<const float4*>(cls)[v];
    int lx = 0, ly = 0, lz = 0, lw = 0;
    #pragma unroll
    for (int c = 1; c < NCLS; ++c) {
      float4 x = reinterpret_cast<const float4*>(cls + (size_t)c * NBOX)[v];
      if (x.x > m.x) { m.x = x.x; lx = c; }
      if (x.y > m.y) { m.y = x.y; ly = c; }
      if (x.z > m.z) { m.z = x.z; lz = c; }
      if (x.w > m.w) { m.w = x.w; lw = c; }
    }
    float s[4] = {m.x, m.y, m.z, m.w};
    uint32_t u4[4];
    #pragma unroll
    for (int q = 0; q < 4; ++q) {
      float ms = (s[q] >= 0.1f) ? s[q] : -1.0f;
      uint32_t u = ~f2ord(ms);
      u4[q] = u;
      atomicAdd(&lh[u >> 24], 1u);
    }
    reinterpret_cast<uint4*>(keys)[v] = make_uint4(u4[0], u4[1], u4[2], u4[3]);
    uchar4 lb; lb.x = (uint8_t)lx; lb.y = (uint8_t)ly; lb.z = (uint8_t)lz; lb.w = (uint8_t)lw;
    reinterpret_cast<uchar4*>(labs)[v] = lb;
  }
  __syncthreads();
  for (int i = threadIdx.x; i < 256; i += blockDim.x)
    if (lh[i]) atomicAdd(&hist0[i], lh[i]);
}

// byte1 histogram among byte0==b1 (b1 recomputed per block from hist0)
__global__ void k_hist1(const uint32_t* __restrict__ keys,
                        const uint32_t* __restrict__ hist0, uint32_t* __restrict__ hist1) {
  __shared__ uint32_t lh[256];
  __shared__ uint32_t sb1;
  if (threadIdx.x == 0) { uint32_t nd; sb1 = scan256(hist0, KPRE, &nd); }
  for (int i = threadIdx.x; i < 256; i += blockDim.x) lh[i] = 0;
  __syncthreads();
  uint32_t b1 = sb1;
  for (int i = blockIdx.x * blockDim.x + threadIdx.x; i < NBOX; i += gridDim.x * blockDim.x) {
    uint32_t u = keys[i];
    if ((u >> 24) == b1) atomicAdd(&lh[(u >> 16) & 0xffu], 1u);
  }
  __syncthreads();
  for (int i = threadIdx.x; i < 256; i += blockDim.x)
    if (lh[i]) atomicAdd(&hist1[i], lh[i]);
}

// compact all keys with top16 <= (b1,b2) into segment blockIdx&63; byte2 histogram
__global__ void k_compact_hist2(const uint32_t* __restrict__ keys,
                                const uint32_t* __restrict__ hist, uint32_t* __restrict__ hist2,
                                unsigned long long* __restrict__ cand,
                                uint32_t* __restrict__ cntc) {
  __shared__ uint32_t lh[256];
  __shared__ uint32_t sp16;
  if (threadIdx.x == 0) {
    uint32_t nd1, nd2;
    uint32_t b1 = scan256(hist, KPRE, &nd1);
    uint32_t b2 = scan256(hist + 256, nd1, &nd2);
    sp16 = (b1 << 8) | b2;
  }
  for (int i = threadIdx.x; i < 256; i += blockDim.x) lh[i] = 0;
  __syncthreads();
  uint32_t p16 = sp16;
  int seg = blockIdx.x & (NSEG - 1);
  uint32_t* ctr = cntc + seg * CSTR;
  unsigned long long* buf = cand + (size_t)seg * SEGC;
  for (int i = blockIdx.x * blockDim.x + threadIdx.x; i < NBOX; i += gridDim.x * blockDim.x) {
    uint32_t u = keys[i];
    uint32_t pref = u >> 16;
    bool take = (pref <= p16);
    unsigned long long key = ((unsigned long long)u << 32) | (uint32_t)i;
    wave_compact(take, key, ctr, buf, SEGC);
    if (take && pref == p16) atomicAdd(&lh[(u >> 8) & 0xffu], 1u);
  }
  __syncthreads();
  for (int i = threadIdx.x; i < 256; i += blockDim.x)
    if (lh[i]) atomicAdd(&hist2[i], lh[i]);
}

// pivot = need3-th smallest key of the 24-bit-exact bucket, via LDS compact + rank-select
__global__ void __launch_bounds__(1024) k_pivot(const unsigned long long* __restrict__ cand,
                                                const uint32_t* __restrict__ cntc,
                                                const uint32_t* __restrict__ hist,
                                                NmsState* st) {
  __shared__ unsigned long long ls[KPRE];
  __shared__ uint32_t scnt[64];
  __shared__ uint32_t lcnt, sp24, sneed;
  int tid = threadIdx.x;
  if (tid < 64) scnt[tid] = min(cntc[tid * CSTR], (uint32_t)SEGC);
  if (tid == 0) {
    uint32_t nd1, nd2, nd3;
    uint32_t b1 = scan256(hist, KPRE, &nd1);
    uint32_t b2 = scan256(hist + 256, nd1, &nd2);
    uint32_t b3 = scan256(hist + 512, nd2, &nd3);
    sp24 = (b1 << 16) | (b2 << 8) | b3;
    sneed = nd3;
    lcnt = 0;
  }
  __syncthreads();
  uint32_t p24 = sp24;
  for (int g = 0; g < NSEG; ++g) {
    uint32_t n = scnt[g];
    const unsigned long long* src = cand + (size_t)g * SEGC;
    for (uint32_t i = tid; i < n; i += 1024) {
      unsigned long long key = src[i];
      wave_compact((uint32_t)(key >> 40) == p24, key, &lcnt, ls, (uint32_t)KPRE);
    }
  }
  __syncthreads();
  uint32_t n = min(lcnt, (uint32_t)KPRE), need = sneed;
  // rank-select: 4 candidates per thread, one broadcast pass over all n
  unsigned long long k0 = (tid < (int)n) ? ls[tid] : ~0ull;
  unsigned long long k1 = (tid + 1024 < (int)n) ? ls[tid + 1024] : ~0ull;
  unsigned long long k2 = (tid + 2048 < (int)n) ? ls[tid + 2048] : ~0ull;
  unsigned long long k3 = (tid + 3072 < (int)n) ? ls[tid + 3072] : ~0ull;
  uint32_t r0 = 0, r1 = 0, r2 = 0, r3 = 0;
  for (uint32_t p = 0; p < n; ++p) {
    unsigned long long kp = ls[p];
    r0 += (kp < k0); r1 += (kp < k1); r2 += (kp < k2); r3 += (kp < k3);
  }
  if (tid < (int)n && r0 == need - 1) st->pivot = k0;
  if (tid + 1024 < (int)n && r1 == need - 1) st->pivot = k1;
  if (tid + 2048 < (int)n && r2 == need - 1) st->pivot = k2;
  if (tid + 3072 < (int)n && r3 == need - 1) st->pivot = k3;
}

// select all keys <= pivot from cand segment blockIdx.x (exactly 4096 total)
__global__ void k_select(const unsigned long long* __restrict__ cand,
                         const uint32_t* __restrict__ cntc,
                         const NmsState* __restrict__ st,
                         unsigned long long* __restrict__ sel,
                         uint32_t* __restrict__ cnts) {
  int seg = blockIdx.x;
  uint32_t n = cntc[seg * CSTR]; if (n > SEGC) n = SEGC;
  unsigned long long piv = st->pivot;
  uint32_t* ctr = cnts + seg * CSTR;
  unsigned long long* buf = sel + (size_t)seg * SEG2;
  const unsigned long long* src = cand + (size_t)seg * SEGC;
  for (uint32_t i = threadIdx.x; i < n; i += blockDim.x) {
    unsigned long long key = src[i];
    wave_compact(key <= piv, key, ctr, buf, SEG2);
  }
}

// gather boxes/labels/values for the UNSORTED 4096 (segment-prefix slot order); stash keys
__global__ void __launch_bounds__(1024) k_gather(
    const unsigned long long* __restrict__ sel, const uint32_t* __restrict__ cnts,
    const float* __restrict__ boxes, const uint8_t* __restrict__ labs,
    float* __restrict__ x1a, float* __restrict__ y1a,
    float* __restrict__ x2a, float* __restrict__ y2a,
    float* __restrict__ vala, int* __restrict__ laba,
    unsigned long long* __restrict__ skeys, unsigned long long* __restrict__ vmask) {
  __shared__ uint32_t tmp[64];
  __shared__ uint32_t offs[NSEG + 1];
  int tid = threadIdx.x;
  if (tid < 64) tmp[tid] = min(cnts[tid * CSTR], (uint32_t)SEG2);
  __syncthreads();
  if (tid == 0) {
    uint32_t o = 0;
    for (int g = 0; g < NSEG; ++g) { offs[g] = o; o += tmp[g]; }
    offs[NSEG] = o;
  }
  __syncthreads();
  int t = blockIdx.x * 1024 + tid;
  if (t >= KPRE) return;
  uint32_t total = offs[NSEG];
  unsigned long long key = ~0ull;
  if (t < (int)total) {
    int g = 0;
    while (t >= (int)offs[g + 1]) ++g;
    key = sel[(size_t)g * SEG2 + (t - offs[g])];
  }
  uint32_t idx = (uint32_t)key;
  if (idx >= NBOX) idx = 0;  // safety
  uint32_t u = (uint32_t)(key >> 32);
  float val = ord2f(~u);
  x1a[t] = boxes[idx];
  y1a[t] = boxes[(size_t)NBOX + idx];
  x2a[t] = boxes[(size_t)2 * NBOX + idx];
  y2a[t] = boxes[(size_t)3 * NBOX + idx];
  vala[t] = val;
  laba[t] = (int)labs[idx];
  skeys[t] = key;
  if (val >= 0.1f) atomicOr(&vmask[t >> 6], 1ull << (t & 63));
}

// sparse suppression pairs: directed (suppressor<<16)|suppressed, direction by key order
__global__ void k_pairs(const float* __restrict__ x1a, const float* __restrict__ y1a,
                        const float* __restrict__ x2a, const float* __restrict__ y2a,
                        const unsigned long long* __restrict__ skeys,
                        uint32_t* __restrict__ pcnt, uint32_t* __restrict__ pairs) {
#pragma clang fp contract(off)
  int bx = blockIdx.x, by = blockIdx.y;
  if (bx < by) return;
  int t = threadIdx.x;  // 64 threads
  int i = by * 64 + t;
  __shared__ float sx1[64], sy1[64], sx2[64], sy2[64], sar[64];
  __shared__ unsigned long long sk[64];
  int j0 = bx * 64 + t;
  float cx1 = x1a[j0], cy1 = y1a[j0], cx2 = x2a[j0], cy2 = y2a[j0];
  sx1[t] = cx1; sy1[t] = cy1; sx2[t] = cx2; sy2[t] = cy2;
  sar[t] = fmaxf(cx2 - cx1, 0.0f) * fmaxf(cy2 - cy1, 0.0f);
  sk[t] = skeys[j0];
  __syncthreads();
  float x1i = x1a[i], y1i = y1a[i], x2i = x2a[i], y2i = y2a[i];
  unsigned long long rk = skeys[i];
  float ari = fmaxf(x2i - x1i, 0.0f) * fmaxf(y2i - y1i, 0.0f);
  unsigned long long w = 0ull;
  #pragma unroll 8
  for (int jj = 0; jj < 64; ++jj) {
    int j = bx * 64 + jj;
    float iw = fmaxf(fminf(x2i, sx2[jj]) - fmaxf(x1i, sx1[jj]), 0.0f);
    float ih = fmaxf(fminf(y2i, sy2[jj]) - fmaxf(y1i, sy1[jj]), 0.0f);
    float inter = iw * ih;
    float den = ((ari + sar[jj]) - inter) + 1e-8f;  // exact ref op order
    float iou = inter / den;
    if ((iou > 0.5f) && (j > i)) w |= (1ull << jj);
  }
  int seg = (by * 64 + bx) & (NSEG - 1);
  uint32_t* ctr = pcnt + seg * CSTR;
  uint32_t* buf = pairs + (size_t)seg * PSEG;
  while (__ballot(w != 0ull)) {
    bool tk = (w != 0ull);
    uint32_t pr = 0;
    if (tk) {
      int b = __builtin_ctzll(w); w &= w - 1;
      int j = bx * 64 + b;
      bool i_sup = (rk < sk[b]);  // smaller key (higher score / lower orig idx) suppresses
      pr = i_sup ? (((uint32_t)i << 16) | (uint32_t)j)
                 : (((uint32_t)j << 16) | (uint32_t)i);
    }
    wave_compact32(tk, pr, ctr, buf, PSEG);
  }
}

// Jacobi fixpoint of A[i] = V[i] & forall (j->i) in E: !A[j]  (== greedy NMS result),
// then top-500-of-survivors select (byte radix narrowing) + rank-sort + output.
__global__ void __launch_bounds__(1024) k_fix(
    const uint32_t* __restrict__ pcnt, const uint32_t* __restrict__ pairs,
    const unsigned long long* __restrict__ vmask, const unsigned long long* __restrict__ skeys,
    const float* __restrict__ x1a, const float* __restrict__ y1a,
    const float* __restrict__ x2a, const float* __restrict__ y2a,
    const float* __restrict__ vala, const int* __restrict__ laba,
    float* __restrict__ out) {
  __shared__ uint32_t lp[LCAP];
  __shared__ unsigned long long lk[KPRE];
  __shared__ uint32_t soff[NSEG + 1];
  __shared__ uint32_t stmp[64];
  __shared__ unsigned long long validm[64], accm[64];
  __shared__ uint32_t supp[128];
  __shared__ uint32_t chg, use_lds;
  __shared__ uint32_t orlo, orhi, andlo, andhi;
  __shared__ unsigned long long spre;
  __shared__ uint32_t sneed, scnt2;
  __shared__ uint32_t hsel[256];
  __shared__ uint32_t lsel[512];
  int tid = threadIdx.x;

  for (int t = tid; t < KPOST * 6; t += 1024) out[t] = 0.0f;

  if (tid < 64) {
    stmp[tid] = min(pcnt[tid * CSTR], (uint32_t)PSEG);
    validm[tid] = vmask[tid];
    accm[tid] = vmask[tid];
  }
  for (int t = tid; t < KPRE; t += 1024) lk[t] = skeys[t];
  __syncthreads();
  if (tid == 0) {
    uint32_t o = 0;
    for (int g = 0; g < NSEG; ++g) { soff[g] = o; o += stmp[g]; }
    soff[NSEG] = o;
    use_lds = (o <= (uint32_t)LCAP) ? 1u : 0u;
  }
  __syncthreads();
  uint32_t npair = soff[NSEG];
  if (use_lds) {
    for (int g = 0; g < NSEG; ++g) {
      uint32_t o = soff[g], c = soff[g + 1] - o;
      for (uint32_t p = tid; p < c; p += 1024) lp[o + p] = pairs[(size_t)g * PSEG + p];
    }
  }

  while (true) {
    __syncthreads();
    if (tid < 128) supp[tid] = 0;
    if (tid == 0) chg = 0;
    __syncthreads();
    if (use_lds) {
      for (uint32_t p = tid; p < npair; p += 1024) {
        uint32_t pr = lp[p];
        uint32_t i = pr >> 16, j = pr & 0xffffu;
        if ((accm[i >> 6] >> (i & 63)) & 1ull) atomicOr(&supp[j >> 5], 1u << (j & 31));
      }
    } else {
      for (int g = 0; g < NSEG; ++g) {
        uint32_t c = soff[g + 1] - soff[g];
        for (uint32_t p = tid; p < c; p += 1024) {
          uint32_t pr = pairs[(size_t)g * PSEG + p];
          uint32_t i = pr >> 16, j = pr & 0xffffu;
          if ((accm[i >> 6] >> (i & 63)) & 1ull) atomicOr(&supp[j >> 5], 1u << (j & 31));
        }
      }
    }
    __syncthreads();
    if (tid < 64) {
      unsigned long long s = ((unsigned long long)supp[2 * tid + 1] << 32) | supp[2 * tid];
      unsigned long long na = validm[tid] & ~s;
      if (na != accm[tid]) { accm[tid] = na; atomicOr(&chg, 1u); }
    }
    __syncthreads();
    if (chg == 0) break;
  }

  // ---- top-KPOST of survivors by key, then rank-ordered emit ----
  if (tid == 0) {
    uint32_t ns = 0;
    for (int l = 0; l < 64; ++l) ns += (uint32_t)__builtin_popcountll(accm[l]);
    sneed = (ns < (uint32_t)KPOST) ? ns : (uint32_t)KPOST;
    orlo = 0; orhi = 0; andlo = ~0u; andhi = ~0u; scnt2 = 0;
  }
  __syncthreads();
  uint32_t need0 = sneed;
  if (need0 == 0) return;

  for (int t = tid; t < KPRE; t += 1024) {
    if ((accm[t >> 6] >> (t & 63)) & 1ull) {
      unsigned long long k = lk[t];
      atomicOr(&orlo, (uint32_t)k); atomicOr(&orhi, (uint32_t)(k >> 32));
      atomicAnd(&andlo, (uint32_t)k); atomicAnd(&andhi, (uint32_t)(k >> 32));
    }
  }
  __syncthreads();
  unsigned long long vor = ((unsigned long long)orhi << 32) | orlo;
  unsigned long long vand = ((unsigned long long)andhi << 32) | andlo;
  unsigned long long diff = vor ^ vand;
  unsigned long long pre = 0;
  uint32_t need = need0;
  for (int b = 7; b >= 0; --b) {
    uint32_t db = (uint32_t)(diff >> (8 * b)) & 255u;
    if (db == 0) { pre = (pre << 8) | ((uint32_t)(vand >> (8 * b)) & 255u); continue; }
    if (tid < 256) hsel[tid] = 0;
    __syncthreads();
    for (int t = tid; t < KPRE; t += 1024) {
      if ((accm[t >> 6] >> (t & 63)) & 1ull) {
        unsigned long long k = lk[t];
        bool pm = (b == 7) ? true : ((k >> (8 * b + 8)) == pre);
        if (pm) atomicAdd(&hsel[(uint32_t)(k >> (8 * b)) & 255u], 1u);
      }
    }
    __syncthreads();
    if (tid == 0) {
      uint32_t cum = 0, d = 255;
      for (int x = 0; x < 256; ++x) {
        uint32_t c = hsel[x];
        if (cum + c >= need) { d = (uint32_t)x; sneed = need - cum; break; }
        cum += c;
      }
      spre = (pre << 8) | d;
    }
    __syncthreads();
    pre = spre; need = sneed;
    __syncthreads();
  }
  unsigned long long T = pre;  // exact key of the need0-th smallest survivor

  for (int t = tid; t < KPRE; t += 1024) {
    bool take = ((accm[t >> 6] >> (t & 63)) & 1ull) && (lk[t] <= T);
    wave_compact32(take, (uint32_t)t, &scnt2, lsel, 512u);
  }
  __syncthreads();
  uint32_t cnt = min(scnt2, 512u);
  if (tid < (int)cnt) {
    uint32_t slot = lsel[tid];
    unsigned long long k0 = lk[slot];
    uint32_t rank = 0;
    for (uint32_t p = 0; p < cnt; ++p) {
      unsigned long long kp = lk[lsel[p]];
      rank += (kp < k0) ? 1u : 0u;
    }
    if (rank < (uint32_t)KPOST) {
      int i = (int)slot;
      out[rank * 6 + 0] = x1a[i];
      out[rank * 6 + 1] = y1a[i];
      out[rank * 6 + 2] = x2a[i];
      out[rank * 6 + 3] = y2a[i];
      out[rank * 6 + 4] = vala[i];
      out[rank * 6 + 5] = (float)laba[i];
    }
  }
}

extern "C" void kernel_launch(void* const* d_in, const int* in_sizes, int n_in,
                              void* d_out, int out_size, void* d_ws, size_t ws_size,
                              hipStream_t stream) {
  const float* boxes = (const float*)d_in[0];
  const float* cls   = (const float*)d_in[1];
  float* out = (float*)d_out;
  char* ws = (char*)d_ws;

  uint32_t* keys = (uint32_t*)(ws + OFF_KEYS);
  unsigned long long* cand  = (unsigned long long*)(ws + OFF_CAND);
  unsigned long long* sel   = (unsigned long long*)(ws + OFF_SEL);
  unsigned long long* skeys = (unsigned long long*)(ws + OFF_SKEYS);
  uint32_t* pairs = (uint32_t*)(ws + OFF_PAIRS);
  unsigned long long* vmask = (unsigned long long*)(ws + OFF_VMASK);
  uint32_t* hist = (uint32_t*)(ws + OFF_HIST);
  uint32_t* cnts = (uint32_t*)(ws + OFF_CNTS);
  uint32_t* cntc  = cnts;                    // cand counters
  uint32_t* cnts3 = cnts + NSEG * CSTR;      // sel counters
  uint32_t* pcnt  = cnts + 2 * NSEG * CSTR;  // pair counters
  NmsState* st = (NmsState*)(ws + OFF_STATE);
  float* x1a = (float*)(ws + OFF_ARR);
  float* y1a = x1a + KPRE;
  float* x2a = y1a + KPRE;
  float* y2a = x2a + KPRE;
  float* vala = y2a + KPRE;
  int*   laba = (int*)(vala + KPRE);
  uint8_t* labs = (uint8_t*)(ws + OFF_LAB);

  k_zero<<<1, 256, 0, stream>>>(hist, st, vmask, cnts);
  k_score<<<1024, 256, 0, stream>>>(cls, keys, labs, hist);
  k_hist1<<<1024, 256, 0, stream>>>(keys, hist, hist + 256);
  k_compact_hist2<<<1024, 256, 0, stream>>>(keys, hist, hist + 512, cand, cntc);
  k_pivot<<<1, 1024, 0, stream>>>(cand, cntc, hist, st);
  k_select<<<NSEG, 256, 0, stream>>>(cand, cntc, st, sel, cnts3);
  k_gather<<<4, 1024, 0, stream>>>(sel, cnts3, boxes, labs, x1a, y1a, x2a, y2a,
                                   vala, laba, skeys, vmask);
  k_pairs<<<dim3(64, 64), 64, 0, stream>>>(x1a, y1a, x2a, y2a, skeys, pcnt, pairs);
  k_fix<<<1, 1024, 0, stream>>>(pcnt, pairs, vmask, skeys, x1a, y1a, x2a, y2a,
                                vala, laba, out);
}

// Round 7
// 409.930 us; speedup vs baseline: 1.1110x; 1.1110x over previous
//
#include <hip/hip_runtime.h>
#include <stdint.h>

#define NBOX 2000000
#define NCLS 10
#define KPRE 4096
#define KPOST 500
#define NSEG 64
#define SEGC 4096   // cand per-segment cap
#define SEG2 1024   // sel per-segment cap
#define PSEG 2048   // pairs per-segment cap
#define LCAP 16384  // LDS pair cache (64 KB)
#define CSTR 16     // counter stride in u32 (one 64B cacheline per counter)

// ---- workspace layout (bytes) ----
#define OFF_KEYS   ((size_t)0)                               // NBOX*4 (u32 ord; idx implicit)
#define OFF_CAND   ((size_t)8000000)
#define OFF_SEL    (OFF_CAND  + (size_t)NSEG * SEGC * 8)
#define OFF_SKEYS  (OFF_SEL   + (size_t)NSEG * SEG2 * 8)
#define OFF_PAIRS  (OFF_SKEYS + (size_t)KPRE * 8)
#define OFF_VMASK  (OFF_PAIRS + (size_t)NSEG * PSEG * 4)
#define OFF_HIST   (OFF_VMASK + (size_t)64 * 8)
#define OFF_CNTS   (OFF_HIST  + (size_t)768 * 4)             // 3*64 counters, 64B stride
#define OFF_STATE  (OFF_CNTS  + (size_t)3 * NSEG * CSTR * 4)
#define OFF_ARR    (OFF_STATE + (size_t)64)
#define OFF_LAB    (OFF_ARR   + (size_t)KPRE * 24)           // NBOX u8 labels

struct NmsState {
  uint32_t b1, need1, p16, need2, p24, need3, pad0, pad1;
  unsigned long long pivot;
};

__device__ __forceinline__ uint32_t f2ord(float f) {
  uint32_t b = __float_as_uint(f);
  return (b & 0x80000000u) ? ~b : (b | 0x80000000u);
}
__device__ __forceinline__ float ord2f(uint32_t ord) {
  uint32_t b = (ord & 0x80000000u) ? (ord ^ 0x80000000u) : ~ord;
  return __uint_as_float(b);
}

// wave-aggregated compaction (u64 payload): one atomic per wave
__device__ __forceinline__ void wave_compact(bool take, unsigned long long key,
                                             uint32_t* counter, unsigned long long* buf,
                                             uint32_t cap) {
  unsigned long long mm = __ballot(take);
  if (take) {
    int lane = threadIdx.x & 63;
    unsigned long long lt = (lane == 0) ? 0ull : (~0ull >> (64 - lane));
    int rank = __builtin_popcountll(mm & lt);
    int leader = __builtin_ctzll(mm);
    uint32_t base = 0;
    if (rank == 0) base = atomicAdd(counter, (uint32_t)__builtin_popcountll(mm));
    base = __shfl(base, leader);
    uint32_t pos = base + (uint32_t)rank;
    if (pos < cap) buf[pos] = key;
  }
}

// wave-aggregated compaction (u32 payload)
__device__ __forceinline__ void wave_compact32(bool take, uint32_t key,
                                               uint32_t* counter, uint32_t* buf,
                                               uint32_t cap) {
  unsigned long long mm = __ballot(take);
  if (take) {
    int lane = threadIdx.x & 63;
    unsigned long long lt = (lane == 0) ? 0ull : (~0ull >> (64 - lane));
    int rank = __builtin_popcountll(mm & lt);
    int leader = __builtin_ctzll(mm);
    uint32_t base = 0;
    if (rank == 0) base = atomicAdd(counter, (uint32_t)__builtin_popcountll(mm));
    base = __shfl(base, leader);
    uint32_t pos = base + (uint32_t)rank;
    if (pos < cap) buf[pos] = key;
  }
}

// ---------------- kernels ----------------

__global__ void k_zero(uint32_t* hist, NmsState* st, unsigned long long* vmask,
                       uint32_t* cnts) {
  int t = threadIdx.x;
  for (int i = t; i < 768; i += blockDim.x) hist[i] = 0;
  for (int i = t; i < 3 * NSEG * CSTR; i += blockDim.x) cnts[i] = 0;
  if (t < 64) vmask[t] = 0;
  if (t == 0) { st->pivot = 0; st->b1 = 0; st->need1 = 0; st->p16 = 0; st->need2 = 0;
                st->p24 = 0; st->need3 = 0; }
}

// scores (max over classes) -> u32 ord keys + per-box argmax label + byte0 histogram
__global__ void k_score(const float* __restrict__ cls, uint32_t* __restrict__ keys,
                        uint8_t* __restrict__ labs, uint32_t* __restrict__ hist0) {
  __shared__ uint32_t lh[256];
  for (int i = threadIdx.x; i < 256; i += blockDim.x) lh[i] = 0;
  __syncthreads();
  const int nvec = NBOX / 4;
  for (int v = blockIdx.x * blockDim.x + threadIdx.x; v < nvec; v += gridDim.x * blockDim.x) {
    float4 m = reinterpret_cast<const float4*>(cls)[v];
    int lx = 0, ly = 0, lz = 0, lw = 0;
    #pragma unroll
    for (int c = 1; c < NCLS; ++c) {
      float4 x = reinterpret_cast<const float4*>(cls + (size_t)c * NBOX)[v];
      if (x.x > m.x) { m.x = x.x; lx = c; }
      if (x.y > m.y) { m.y = x.y; ly = c; }
      if (x.z > m.z) { m.z = x.z; lz = c; }
      if (x.w > m.w) { m.w = x.w; lw = c; }
    }
    float s[4] = {m.x, m.y, m.z, m.w};
    uint32_t u4[4];
    #pragma unroll
    for (int q = 0; q < 4; ++q) {
      float ms = (s[q] >= 0.1f) ? s[q] : -1.0f;
      uint32_t u = ~f2ord(ms);
      u4[q] = u;
      atomicAdd(&lh[u >> 24], 1u);
    }
    reinterpret_cast<uint4*>(keys)[v] = make_uint4(u4[0], u4[1], u4[2], u4[3]);
    uchar4 lb; lb.x = (uint8_t)lx; lb.y = (uint8_t)ly; lb.z = (uint8_t)lz; lb.w = (uint8_t)lw;
    reinterpret_cast<uchar4*>(labs)[v] = lb;
  }
  __syncthreads();
  for (int i = threadIdx.x; i < 256; i += blockDim.x)
    if (lh[i]) atomicAdd(&hist0[i], lh[i]);
}

// one wave: find bucket of the need-th smallest in hist[256] via shfl prefix-sum
__global__ void k_thresh(const uint32_t* __restrict__ hist, NmsState* st, int stage) {
  int l = threadIdx.x;  // 64 lanes
  uint4 h4 = reinterpret_cast<const uint4*>(hist)[l];
  uint32_t s = h4.x + h4.y + h4.z + h4.w;
  uint32_t p = s;
  #pragma unroll
  for (int d = 1; d < 64; d <<= 1) {
    uint32_t v = __shfl_up(p, d, 64);
    if (l >= d) p += v;
  }
  uint32_t exc = p - s;
  uint32_t need = (stage == 0) ? (uint32_t)KPRE : (stage == 1 ? st->need1 : st->need2);
  uint32_t e0 = exc, e1 = e0 + h4.x, e2 = e1 + h4.y, e3 = e2 + h4.z, e4 = e3 + h4.w;
  uint32_t eb[5] = {e0, e1, e2, e3, e4};
  #pragma unroll
  for (int q = 0; q < 4; ++q) {
    if (eb[q] < need && need <= eb[q + 1]) {
      uint32_t bin = (uint32_t)(4 * l + q), nd = need - eb[q];
      if (stage == 0)      { st->b1 = bin; st->need1 = nd; }
      else if (stage == 1) { st->p16 = (st->b1 << 8) | bin; st->need2 = nd; }
      else                 { st->p24 = (st->p16 << 8) | bin; st->need3 = nd; }
    }
  }
}

// byte1 histogram among byte0==b1
__global__ void k_hist1(const uint32_t* __restrict__ keys,
                        const NmsState* __restrict__ st, uint32_t* __restrict__ hist1) {
  __shared__ uint32_t lh[256];
  for (int i = threadIdx.x; i < 256; i += blockDim.x) lh[i] = 0;
  __syncthreads();
  uint32_t b1 = st->b1;
  for (int i = blockIdx.x * blockDim.x + threadIdx.x; i < NBOX; i += gridDim.x * blockDim.x) {
    uint32_t u = keys[i];
    if ((u >> 24) == b1) atomicAdd(&lh[(u >> 16) & 0xffu], 1u);
  }
  __syncthreads();
  for (int i = threadIdx.x; i < 256; i += blockDim.x)
    if (lh[i]) atomicAdd(&hist1[i], lh[i]);
}

// compact all keys with top16 <= p16 into segment blockIdx&63; byte2 histogram
__global__ void k_compact_hist2(const uint32_t* __restrict__ keys,
                                const NmsState* __restrict__ st, uint32_t* __restrict__ hist2,
                                unsigned long long* __restrict__ cand,
                                uint32_t* __restrict__ cntc) {
  __shared__ uint32_t lh[256];
  for (int i = threadIdx.x; i < 256; i += blockDim.x) lh[i] = 0;
  __syncthreads();
  uint32_t p16 = st->p16;
  int seg = blockIdx.x & (NSEG - 1);
  uint32_t* ctr = cntc + seg * CSTR;
  unsigned long long* buf = cand + (size_t)seg * SEGC;
  for (int i = blockIdx.x * blockDim.x + threadIdx.x; i < NBOX; i += gridDim.x * blockDim.x) {
    uint32_t u = keys[i];
    uint32_t pref = u >> 16;
    bool take = (pref <= p16);
    unsigned long long key = ((unsigned long long)u << 32) | (uint32_t)i;
    wave_compact(take, key, ctr, buf, SEGC);
    if (take && pref == p16) atomicAdd(&lh[(u >> 8) & 0xffu], 1u);
  }
  __syncthreads();
  for (int i = threadIdx.x; i < 256; i += blockDim.x)
    if (lh[i]) atomicAdd(&hist2[i], lh[i]);
}

// pivot = need3-th smallest key of the 24-bit-exact bucket, via LDS compact + rank-select
__global__ void __launch_bounds__(1024) k_pivot(const unsigned long long* __restrict__ cand,
                                                const uint32_t* __restrict__ cntc,
                                                NmsState* st) {
  __shared__ unsigned long long ls[KPRE];
  __shared__ uint32_t scnt[64];
  __shared__ uint32_t lcnt;
  int tid = threadIdx.x;
  if (tid < 64) scnt[tid] = min(cntc[tid * CSTR], (uint32_t)SEGC);
  if (tid == 0) lcnt = 0;
  __syncthreads();
  uint32_t p24 = st->p24, need = st->need3;
  for (int g = 0; g < NSEG; ++g) {
    uint32_t n = scnt[g];
    const unsigned long long* src = cand + (size_t)g * SEGC;
    for (uint32_t i = tid; i < n; i += 1024) {
      unsigned long long key = src[i];
      wave_compact((uint32_t)(key >> 40) == p24, key, &lcnt, ls, (uint32_t)KPRE);
    }
  }
  __syncthreads();
  uint32_t n = min(lcnt, (uint32_t)KPRE);
  unsigned long long k0 = (tid < (int)n) ? ls[tid] : ~0ull;
  unsigned long long k1 = (tid + 1024 < (int)n) ? ls[tid + 1024] : ~0ull;
  unsigned long long k2 = (tid + 2048 < (int)n) ? ls[tid + 2048] : ~0ull;
  unsigned long long k3 = (tid + 3072 < (int)n) ? ls[tid + 3072] : ~0ull;
  uint32_t r0 = 0, r1 = 0, r2 = 0, r3 = 0;
  for (uint32_t p = 0; p < n; ++p) {
    unsigned long long kp = ls[p];
    r0 += (kp < k0); r1 += (kp < k1); r2 += (kp < k2); r3 += (kp < k3);
  }
  if (tid < (int)n && r0 == need - 1) st->pivot = k0;
  if (tid + 1024 < (int)n && r1 == need - 1) st->pivot = k1;
  if (tid + 2048 < (int)n && r2 == need - 1) st->pivot = k2;
  if (tid + 3072 < (int)n && r3 == need - 1) st->pivot = k3;
}

// select all keys <= pivot from cand segment blockIdx.x (exactly 4096 total)
__global__ void k_select(const unsigned long long* __restrict__ cand,
                         const uint32_t* __restrict__ cntc,
                         const NmsState* __restrict__ st,
                         unsigned long long* __restrict__ sel,
                         uint32_t* __restrict__ cnts) {
  int seg = blockIdx.x;
  uint32_t n = cntc[seg * CSTR]; if (n > SEGC) n = SEGC;
  unsigned long long piv = st->pivot;
  uint32_t* ctr = cnts + seg * CSTR;
  unsigned long long* buf = sel + (size_t)seg * SEG2;
  const unsigned long long* src = cand + (size_t)seg * SEGC;
  for (uint32_t i = threadIdx.x; i < n; i += blockDim.x) {
    unsigned long long key = src[i];
    wave_compact(key <= piv, key, ctr, buf, SEG2);
  }
}

// gather boxes/labels/values for the UNSORTED 4096 (segment-prefix slot order); stash keys
__global__ void __launch_bounds__(1024) k_gather(
    const unsigned long long* __restrict__ sel, const uint32_t* __restrict__ cnts,
    const float* __restrict__ boxes, const uint8_t* __restrict__ labs,
    float* __restrict__ x1a, float* __restrict__ y1a,
    float* __restrict__ x2a, float* __restrict__ y2a,
    float* __restrict__ vala, int* __restrict__ laba,
    unsigned long long* __restrict__ skeys, unsigned long long* __restrict__ vmask) {
  __shared__ uint32_t tmp[64];
  __shared__ uint32_t offs[NSEG + 1];
  int tid = threadIdx.x;
  if (tid < 64) tmp[tid] = min(cnts[tid * CSTR], (uint32_t)SEG2);
  __syncthreads();
  if (tid == 0) {
    uint32_t o = 0;
    for (int g = 0; g < NSEG; ++g) { offs[g] = o; o += tmp[g]; }
    offs[NSEG] = o;
  }
  __syncthreads();
  int t = blockIdx.x * 1024 + tid;
  if (t >= KPRE) return;
  uint32_t total = offs[NSEG];
  unsigned long long key = ~0ull;
  if (t < (int)total) {
    int g = 0;
    while (t >= (int)offs[g + 1]) ++g;
    key = sel[(size_t)g * SEG2 + (t - offs[g])];
  }
  uint32_t idx = (uint32_t)key;
  if (idx >= NBOX) idx = 0;  // safety
  uint32_t u = (uint32_t)(key >> 32);
  float val = ord2f(~u);
  x1a[t] = boxes[idx];
  y1a[t] = boxes[(size_t)NBOX + idx];
  x2a[t] = boxes[(size_t)2 * NBOX + idx];
  y2a[t] = boxes[(size_t)3 * NBOX + idx];
  vala[t] = val;
  laba[t] = (int)labs[idx];
  skeys[t] = key;
  if (val >= 0.1f) atomicOr(&vmask[t >> 6], 1ull << (t & 63));
}

// sparse suppression pairs: directed (suppressor<<16)|suppressed, direction by key order
__global__ void k_pairs(const float* __restrict__ x1a, const float* __restrict__ y1a,
                        const float* __restrict__ x2a, const float* __restrict__ y2a,
                        const unsigned long long* __restrict__ skeys,
                        uint32_t* __restrict__ pcnt, uint32_t* __restrict__ pairs) {
#pragma clang fp contract(off)
  int bx = blockIdx.x, by = blockIdx.y;
  if (bx < by) return;
  int t = threadIdx.x;  // 64 threads
  int i = by * 64 + t;
  __shared__ float sx1[64], sy1[64], sx2[64], sy2[64], sar[64];
  __shared__ unsigned long long sk[64];
  int j0 = bx * 64 + t;
  float cx1 = x1a[j0], cy1 = y1a[j0], cx2 = x2a[j0], cy2 = y2a[j0];
  sx1[t] = cx1; sy1[t] = cy1; sx2[t] = cx2; sy2[t] = cy2;
  sar[t] = fmaxf(cx2 - cx1, 0.0f) * fmaxf(cy2 - cy1, 0.0f);
  sk[t] = skeys[j0];
  __syncthreads();
  float x1i = x1a[i], y1i = y1a[i], x2i = x2a[i], y2i = y2a[i];
  unsigned long long rk = skeys[i];
  float ari = fmaxf(x2i - x1i, 0.0f) * fmaxf(y2i - y1i, 0.0f);
  unsigned long long w = 0ull;
  #pragma unroll 8
  for (int jj = 0; jj < 64; ++jj) {
    int j = bx * 64 + jj;
    float iw = fmaxf(fminf(x2i, sx2[jj]) - fmaxf(x1i, sx1[jj]), 0.0f);
    float ih = fmaxf(fminf(y2i, sy2[jj]) - fmaxf(y1i, sy1[jj]), 0.0f);
    float inter = iw * ih;
    float den = ((ari + sar[jj]) - inter) + 1e-8f;  // exact ref op order
    float iou = inter / den;
    if ((iou > 0.5f) && (j > i)) w |= (1ull << jj);
  }
  int seg = (by * 64 + bx) & (NSEG - 1);
  uint32_t* ctr = pcnt + seg * CSTR;
  uint32_t* buf = pairs + (size_t)seg * PSEG;
  while (__ballot(w != 0ull)) {
    bool tk = (w != 0ull);
    uint32_t pr = 0;
    if (tk) {
      int b = __builtin_ctzll(w); w &= w - 1;
      int j = bx * 64 + b;
      bool i_sup = (rk < sk[b]);  // smaller key (higher score / lower orig idx) suppresses
      pr = i_sup ? (((uint32_t)i << 16) | (uint32_t)j)
                 : (((uint32_t)j << 16) | (uint32_t)i);
    }
    wave_compact32(tk, pr, ctr, buf, PSEG);
  }
}

// Jacobi fixpoint of A[i] = V[i] & forall (j->i) in E: !A[j]  (== greedy NMS result),
// then top-500-of-survivors select (radix narrowing, wave-parallel scans) + rank emit.
__global__ void __launch_bounds__(1024) k_fix(
    const uint32_t* __restrict__ pcnt, const uint32_t* __restrict__ pairs,
    const unsigned long long* __restrict__ vmask, const unsigned long long* __restrict__ skeys,
    const float* __restrict__ x1a, const float* __restrict__ y1a,
    const float* __restrict__ x2a, const float* __restrict__ y2a,
    const float* __restrict__ vala, const int* __restrict__ laba,
    float* __restrict__ out) {
  __shared__ uint32_t lp[LCAP];
  __shared__ unsigned long long lk[KPRE];
  __shared__ uint32_t soff[NSEG + 1];
  __shared__ uint32_t stmp[64];
  __shared__ unsigned long long validm[64], accm[64];
  __shared__ uint32_t supp[128];
  __shared__ uint32_t chg, use_lds;
  __shared__ uint32_t orlo, orhi, andlo, andhi;
  __shared__ unsigned long long spre;
  __shared__ uint32_t sneed, scnt2;
  __shared__ uint32_t hsel[256];
  __shared__ uint32_t lsel[512];
  __shared__ unsigned long long kkbuf[512];
  int tid = threadIdx.x;

  for (int t = tid; t < KPOST * 6; t += 1024) out[t] = 0.0f;

  if (tid < 64) {
    stmp[tid] = min(pcnt[tid * CSTR], (uint32_t)PSEG);
    validm[tid] = vmask[tid];
    accm[tid] = vmask[tid];
  }
  for (int t = tid; t < KPRE; t += 1024) lk[t] = skeys[t];
  __syncthreads();
  if (tid == 0) {
    uint32_t o = 0;
    for (int g = 0; g < NSEG; ++g) { soff[g] = o; o += stmp[g]; }
    soff[NSEG] = o;
    use_lds = (o <= (uint32_t)LCAP) ? 1u : 0u;
  }
  __syncthreads();
  uint32_t npair = soff[NSEG];
  if (use_lds) {
    for (int g = 0; g < NSEG; ++g) {
      uint32_t o = soff[g], c = soff[g + 1] - o;
      for (uint32_t p = tid; p < c; p += 1024) lp[o + p] = pairs[(size_t)g * PSEG + p];
    }
  }

  while (true) {
    __syncthreads();
    if (tid < 128) supp[tid] = 0;
    if (tid == 0) chg = 0;
    __syncthreads();
    if (use_lds) {
      for (uint32_t p = tid; p < npair; p += 1024) {
        uint32_t pr = lp[p];
        uint32_t i = pr >> 16, j = pr & 0xffffu;
        if ((accm[i >> 6] >> (i & 63)) & 1ull) atomicOr(&supp[j >> 5], 1u << (j & 31));
      }
    } else {
      for (int g = 0; g < NSEG; ++g) {
        uint32_t c = soff[g + 1] - soff[g];
        for (uint32_t p = tid; p < c; p += 1024) {
          uint32_t pr = pairs[(size_t)g * PSEG + p];
          uint32_t i = pr >> 16, j = pr & 0xffffu;
          if ((accm[i >> 6] >> (i & 63)) & 1ull) atomicOr(&supp[j >> 5], 1u << (j & 31));
        }
      }
    }
    __syncthreads();
    if (tid < 64) {
      unsigned long long s = ((unsigned long long)supp[2 * tid + 1] << 32) | supp[2 * tid];
      unsigned long long na = validm[tid] & ~s;
      if (na != accm[tid]) { accm[tid] = na; atomicOr(&chg, 1u); }
    }
    __syncthreads();
    if (chg == 0) break;
  }

  // ---- top-KPOST of survivors by key (radix narrowing), then rank-ordered emit ----
  if (tid == 0) {
    uint32_t ns = 0;
    for (int l = 0; l < 64; ++l) ns += (uint32_t)__builtin_popcountll(accm[l]);
    sneed = (ns < (uint32_t)KPOST) ? ns : (uint32_t)KPOST;
    orlo = 0; orhi = 0; andlo = ~0u; andhi = ~0u; scnt2 = 0;
  }
  __syncthreads();
  uint32_t need0 = sneed;
  if (need0 == 0) return;

  for (int t = tid; t < KPRE; t += 1024) {
    if ((accm[t >> 6] >> (t & 63)) & 1ull) {
      unsigned long long k = lk[t];
      atomicOr(&orlo, (uint32_t)k); atomicOr(&orhi, (uint32_t)(k >> 32));
      atomicAnd(&andlo, (uint32_t)k); atomicAnd(&andhi, (uint32_t)(k >> 32));
    }
  }
  __syncthreads();
  unsigned long long vor = ((unsigned long long)orhi << 32) | orlo;
  unsigned long long vand = ((unsigned long long)andhi << 32) | andlo;
  unsigned long long diff = vor ^ vand;
  unsigned long long pre = 0;
  uint32_t need = need0;
  for (int b = 7; b >= 0; --b) {
    uint32_t db = (uint32_t)(diff >> (8 * b)) & 255u;
    if (db == 0) { pre = (pre << 8) | ((uint32_t)(vand >> (8 * b)) & 255u); continue; }
    if (tid < 256) hsel[tid] = 0;
    __syncthreads();
    for (int t = tid; t < KPRE; t += 1024) {
      if ((accm[t >> 6] >> (t & 63)) & 1ull) {
        unsigned long long k = lk[t];
        bool pm = (b == 7) ? true : ((k >> (8 * b + 8)) == pre);
        if (pm) atomicAdd(&hsel[(uint32_t)(k >> (8 * b)) & 255u], 1u);
      }
    }
    __syncthreads();
    if (tid < 64) {  // wave-parallel 256-bin select (4 bins/lane, shfl prefix)
      uint32_t c0 = hsel[4 * tid], c1 = hsel[4 * tid + 1],
               c2 = hsel[4 * tid + 2], c3 = hsel[4 * tid + 3];
      uint32_t s = c0 + c1 + c2 + c3;
      uint32_t p = s;
      #pragma unroll
      for (int d = 1; d < 64; d <<= 1) {
        uint32_t v = __shfl_up(p, d, 64);
        if (tid >= d) p += v;
      }
      uint32_t e0 = p - s, e1 = e0 + c0, e2 = e1 + c1, e3 = e2 + c2, e4 = e3 + c3;
      uint32_t eb[5] = {e0, e1, e2, e3, e4};
      #pragma unroll
      for (int q = 0; q < 4; ++q) {
        if (eb[q] < need && need <= eb[q + 1]) {
          spre = (pre << 8) | (uint32_t)(4 * tid + q);
          sneed = need - eb[q];
        }
      }
    }
    __syncthreads();
    pre = spre; need = sneed;
    __syncthreads();
  }
  unsigned long long T = pre;  // exact key of the need0-th smallest survivor

  for (int t = tid; t < KPRE; t += 1024) {
    bool take = ((accm[t >> 6] >> (t & 63)) & 1ull) && (lk[t] <= T);
    wave_compact32(take, (uint32_t)t, &scnt2, lsel, 512u);
  }
  __syncthreads();
  uint32_t cnt = min(scnt2, 512u);
  if (tid < (int)cnt) kkbuf[tid] = lk[lsel[tid]];
  __syncthreads();
  if (tid < (int)cnt) {
    unsigned long long k0 = kkbuf[tid];
    uint32_t rank = 0;
    for (uint32_t p = 0; p < cnt; ++p) rank += (kkbuf[p] < k0) ? 1u : 0u;
    if (rank < (uint32_t)KPOST) {
      int i = (int)lsel[tid];
      out[rank * 6 + 0] = x1a[i];
      out[rank * 6 + 1] = y1a[i];
      out[rank * 6 + 2] = x2a[i];
      out[rank * 6 + 3] = y2a[i];
      out[rank * 6 + 4] = vala[i];
      out[rank * 6 + 5] = (float)laba[i];
    }
  }
}

extern "C" void kernel_launch(void* const* d_in, const int* in_sizes, int n_in,
                              void* d_out, int out_size, void* d_ws, size_t ws_size,
                              hipStream_t stream) {
  const float* boxes = (const float*)d_in[0];
  const float* cls   = (const float*)d_in[1];
  float* out = (float*)d_out;
  char* ws = (char*)d_ws;

  uint32_t* keys = (uint32_t*)(ws + OFF_KEYS);
  unsigned long long* cand  = (unsigned long long*)(ws + OFF_CAND);
  unsigned long long* sel   = (unsigned long long*)(ws + OFF_SEL);
  unsigned long long* skeys = (unsigned long long*)(ws + OFF_SKEYS);
  uint32_t* pairs = (uint32_t*)(ws + OFF_PAIRS);
  unsigned long long* vmask = (unsigned long long*)(ws + OFF_VMASK);
  uint32_t* hist = (uint32_t*)(ws + OFF_HIST);
  uint32_t* cnts = (uint32_t*)(ws + OFF_CNTS);
  uint32_t* cntc  = cnts;                    // cand counters
  uint32_t* cnts3 = cnts + NSEG * CSTR;      // sel counters
  uint32_t* pcnt  = cnts + 2 * NSEG * CSTR;  // pair counters
  NmsState* st = (NmsState*)(ws + OFF_STATE);
  float* x1a = (float*)(ws + OFF_ARR);
  float* y1a = x1a + KPRE;
  float* x2a = y1a + KPRE;
  float* y2a = x2a + KPRE;
  float* vala = y2a + KPRE;
  int*   laba = (int*)(vala + KPRE);
  uint8_t* labs = (uint8_t*)(ws + OFF_LAB);

  k_zero<<<1, 256, 0, stream>>>(hist, st, vmask, cnts);
  k_score<<<1024, 256, 0, stream>>>(cls, keys, labs, hist);
  k_thresh<<<1, 64, 0, stream>>>(hist, st, 0);
  k_hist1<<<1024, 256, 0, stream>>>(keys, st, hist + 256);
  k_thresh<<<1, 64, 0, stream>>>(hist + 256, st, 1);
  k_compact_hist2<<<1024, 256, 0, stream>>>(keys, st, hist + 512, cand, cntc);
  k_thresh<<<1, 64, 0, stream>>>(hist + 512, st, 2);
  k_pivot<<<1, 1024, 0, stream>>>(cand, cntc, st);
  k_select<<<NSEG, 256, 0, stream>>>(cand, cntc, st, sel, cnts3);
  k_gather<<<4, 1024, 0, stream>>>(sel, cnts3, boxes, labs, x1a, y1a, x2a, y2a,
                                   vala, laba, skeys, vmask);
  k_pairs<<<dim3(64, 64), 64, 0, stream>>>(x1a, y1a, x2a, y2a, skeys, pcnt, pairs);
  k_fix<<<1, 1024, 0, stream>>>(pcnt, pairs, vmask, skeys, x1a, y1a, x2a, y2a,
                                vala, laba, out);
}

// Round 8
// 363.117 us; speedup vs baseline: 1.2543x; 1.1289x over previous
//
#include <hip/hip_runtime.h>
#include <stdint.h>

#define NBOX 2000000
#define NCLS 10
#define KPRE 4096
#define KPOST 500
#define NSEG 64
#define SEGC 4096   // cand per-segment cap
#define SEG2 1024   // sel per-segment cap
#define PSEG 2048   // pairs per-segment cap
#define LCAP 16384  // LDS pair cache (64 KB)
#define CSTR 16     // counter stride in u32 (one 64B cacheline per counter)

// ---- workspace layout (bytes) ----
#define OFF_KEYS   ((size_t)0)                               // NBOX*4 (u32 ord; idx implicit)
#define OFF_CAND   ((size_t)8000000)
#define OFF_SEL    (OFF_CAND  + (size_t)NSEG * SEGC * 8)
#define OFF_SKEYS  (OFF_SEL   + (size_t)NSEG * SEG2 * 8)
#define OFF_PAIRS  (OFF_SKEYS + (size_t)KPRE * 8)
#define OFF_VMASK  (OFF_PAIRS + (size_t)NSEG * PSEG * 4)
#define OFF_HIST   (OFF_VMASK + (size_t)64 * 8)
#define OFF_CNTS   (OFF_HIST  + (size_t)768 * 4)             // 3*64 counters, 64B stride
#define OFF_STATE  (OFF_CNTS  + (size_t)3 * NSEG * CSTR * 4)
#define OFF_ARR    (OFF_STATE + (size_t)64)
#define OFF_LAB    (OFF_ARR   + (size_t)KPRE * 24)           // NBOX u8 labels

struct NmsState {
  unsigned long long pivot;
  unsigned long long pad[7];
};

__device__ __forceinline__ uint32_t f2ord(float f) {
  uint32_t b = __float_as_uint(f);
  return (b & 0x80000000u) ? ~b : (b | 0x80000000u);
}
__device__ __forceinline__ float ord2f(uint32_t ord) {
  uint32_t b = (ord & 0x80000000u) ? (ord ^ 0x80000000u) : ~ord;
  return __uint_as_float(b);
}

// executed by one FULL wave (lanes 0..63): bucket of the need-th smallest in h[256]
// returns same (bin, nd) on all lanes. One uint4 load/lane + shfl prefix — no serial scan.
__device__ __forceinline__ void wave_bucket(const uint32_t* __restrict__ h, uint32_t need,
                                            uint32_t* bin_out, uint32_t* nd_out) {
  int l = threadIdx.x & 63;
  uint4 h4 = reinterpret_cast<const uint4*>(h)[l];
  uint32_t s = h4.x + h4.y + h4.z + h4.w;
  uint32_t p = s;
  #pragma unroll
  for (int d = 1; d < 64; d <<= 1) {
    uint32_t v = __shfl_up(p, d, 64);
    if (l >= d) p += v;
  }
  uint32_t e0 = p - s, e1 = e0 + h4.x, e2 = e1 + h4.y, e3 = e2 + h4.z, e4 = e3 + h4.w;
  uint32_t eb[5] = {e0, e1, e2, e3, e4};
  uint32_t bin = 0xFFFFFFFFu, nd = 1;
  #pragma unroll
  for (int q = 0; q < 4; ++q)
    if (eb[q] < need && need <= eb[q + 1]) { bin = (uint32_t)(4 * l + q); nd = need - eb[q]; }
  unsigned long long mm = __ballot(bin != 0xFFFFFFFFu);
  int src = mm ? __builtin_ctzll(mm) : 0;
  *bin_out = (uint32_t)__shfl((int)bin, src);
  *nd_out  = (uint32_t)__shfl((int)nd, src);
}

// wave-aggregated LDS histogram add — fast when bins are near-uniform within the wave
__device__ __forceinline__ void hist_add_wave(uint32_t* lh, uint32_t bin) {
  unsigned long long act = __ballot(1);
  int lane = threadIdx.x & 63;
  unsigned long long rem = act;
  while (rem) {
    int leader = __builtin_ctzll(rem);
    uint32_t lb = __shfl(bin, leader);
    unsigned long long same = __ballot(bin == lb) & act;
    if (lane == leader) atomicAdd(&lh[lb], (uint32_t)__builtin_popcountll(same));
    rem &= ~same;
  }
}

// wave-aggregated compaction (u64 payload): one atomic per wave; works with partial masks
__device__ __forceinline__ void wave_compact(bool take, unsigned long long key,
                                             uint32_t* counter, unsigned long long* buf,
                                             uint32_t cap) {
  unsigned long long mm = __ballot(take);
  if (take) {
    int lane = threadIdx.x & 63;
    unsigned long long lt = (lane == 0) ? 0ull : (~0ull >> (64 - lane));
    int rank = __builtin_popcountll(mm & lt);
    int leader = __builtin_ctzll(mm);
    uint32_t base = 0;
    if (rank == 0) base = atomicAdd(counter, (uint32_t)__builtin_popcountll(mm));
    base = __shfl(base, leader);
    uint32_t pos = base + (uint32_t)rank;
    if (pos < cap) buf[pos] = key;
  }
}

// wave-aggregated compaction (u32 payload)
__device__ __forceinline__ void wave_compact32(bool take, uint32_t key,
                                               uint32_t* counter, uint32_t* buf,
                                               uint32_t cap) {
  unsigned long long mm = __ballot(take);
  if (take) {
    int lane = threadIdx.x & 63;
    unsigned long long lt = (lane == 0) ? 0ull : (~0ull >> (64 - lane));
    int rank = __builtin_popcountll(mm & lt);
    int leader = __builtin_ctzll(mm);
    uint32_t base = 0;
    if (rank == 0) base = atomicAdd(counter, (uint32_t)__builtin_popcountll(mm));
    base = __shfl(base, leader);
    uint32_t pos = base + (uint32_t)rank;
    if (pos < cap) buf[pos] = key;
  }
}

// ---------------- kernels ----------------

__global__ void k_zero(uint32_t* hist, NmsState* st, unsigned long long* vmask,
                       uint32_t* cnts) {
  int t = threadIdx.x;
  for (int i = t; i < 768; i += blockDim.x) hist[i] = 0;
  for (int i = t; i < 3 * NSEG * CSTR; i += blockDim.x) cnts[i] = 0;
  if (t < 64) vmask[t] = 0;
  if (t == 0) st->pivot = 0;
}

// scores (max over classes) -> u32 ord keys + per-box argmax label + byte0 histogram
__global__ void k_score(const float* __restrict__ cls, uint32_t* __restrict__ keys,
                        uint8_t* __restrict__ labs, uint32_t* __restrict__ hist0) {
  __shared__ uint32_t lh[256];
  for (int i = threadIdx.x; i < 256; i += blockDim.x) lh[i] = 0;
  __syncthreads();
  const int nvec = NBOX / 4;
  for (int v = blockIdx.x * blockDim.x + threadIdx.x; v < nvec; v += gridDim.x * blockDim.x) {
    float4 m = reinterpret_cast<const float4*>(cls)[v];
    int lx = 0, ly = 0, lz = 0, lw = 0;
    #pragma unroll
    for (int c = 1; c < NCLS; ++c) {
      float4 x = reinterpret_cast<const float4*>(cls + (size_t)c * NBOX)[v];
      if (x.x > m.x) { m.x = x.x; lx = c; }
      if (x.y > m.y) { m.y = x.y; ly = c; }
      if (x.z > m.z) { m.z = x.z; lz = c; }
      if (x.w > m.w) { m.w = x.w; lw = c; }
    }
    float s[4] = {m.x, m.y, m.z, m.w};
    uint32_t u4[4];
    #pragma unroll
    for (int q = 0; q < 4; ++q) {
      float ms = (s[q] >= 0.1f) ? s[q] : -1.0f;
      uint32_t u = ~f2ord(ms);
      u4[q] = u;
      hist_add_wave(lh, u >> 24);   // bins near-constant (byte0≈0x40) -> 1-2 iters
    }
    reinterpret_cast<uint4*>(keys)[v] = make_uint4(u4[0], u4[1], u4[2], u4[3]);
    uchar4 lb; lb.x = (uint8_t)lx; lb.y = (uint8_t)ly; lb.z = (uint8_t)lz; lb.w = (uint8_t)lw;
    reinterpret_cast<uchar4*>(labs)[v] = lb;
  }
  __syncthreads();
  for (int i = threadIdx.x; i < 256; i += blockDim.x)
    if (lh[i]) atomicAdd(&hist0[i], lh[i]);
}

// byte1 histogram among byte0==b1 (b1 from inline wave-parallel bucket find)
__global__ void k_hist1(const uint32_t* __restrict__ keys,
                        const uint32_t* __restrict__ hist0, uint32_t* __restrict__ hist1) {
  __shared__ uint32_t lh[256];
  __shared__ uint32_t sb1;
  if (threadIdx.x < 64) {
    uint32_t b1, nd1;
    wave_bucket(hist0, KPRE, &b1, &nd1);
    if (threadIdx.x == 0) sb1 = b1;
  }
  for (int i = threadIdx.x; i < 256; i += blockDim.x) lh[i] = 0;
  __syncthreads();
  uint32_t b1 = sb1;
  for (int i = blockIdx.x * blockDim.x + threadIdx.x; i < NBOX; i += gridDim.x * blockDim.x) {
    uint32_t u = keys[i];
    if ((u >> 24) == b1) atomicAdd(&lh[(u >> 16) & 0xffu], 1u);
  }
  __syncthreads();
  for (int i = threadIdx.x; i < 256; i += blockDim.x)
    if (lh[i]) atomicAdd(&hist1[i], lh[i]);
}

// compact all keys with top16 <= p16 into segment blockIdx&63; byte2 histogram
__global__ void k_compact_hist2(const uint32_t* __restrict__ keys,
                                const uint32_t* __restrict__ hist0,
                                const uint32_t* __restrict__ hist1,
                                uint32_t* __restrict__ hist2,
                                unsigned long long* __restrict__ cand,
                                uint32_t* __restrict__ cntc) {
  __shared__ uint32_t lh[256];
  __shared__ uint32_t sp16;
  if (threadIdx.x < 64) {
    uint32_t b1, nd1, b2, nd2;
    wave_bucket(hist0, KPRE, &b1, &nd1);
    wave_bucket(hist1, nd1, &b2, &nd2);
    if (threadIdx.x == 0) sp16 = (b1 << 8) | b2;
  }
  for (int i = threadIdx.x; i < 256; i += blockDim.x) lh[i] = 0;
  __syncthreads();
  uint32_t p16 = sp16;
  int seg = blockIdx.x & (NSEG - 1);
  uint32_t* ctr = cntc + seg * CSTR;
  unsigned long long* buf = cand + (size_t)seg * SEGC;
  for (int i = blockIdx.x * blockDim.x + threadIdx.x; i < NBOX; i += gridDim.x * blockDim.x) {
    uint32_t u = keys[i];
    uint32_t pref = u >> 16;
    bool take = (pref <= p16);
    unsigned long long key = ((unsigned long long)u << 32) | (uint32_t)i;
    wave_compact(take, key, ctr, buf, SEGC);
    if (take && pref == p16) atomicAdd(&lh[(u >> 8) & 0xffu], 1u);
  }
  __syncthreads();
  for (int i = threadIdx.x; i < 256; i += blockDim.x)
    if (lh[i]) atomicAdd(&hist2[i], lh[i]);
}

// pivot = need3-th smallest key of the 24-bit-exact bucket.
// Interleaved segment scan (lane=seg), LDS compact, rank-select.
__global__ void __launch_bounds__(1024) k_pivot(const unsigned long long* __restrict__ cand,
                                                const uint32_t* __restrict__ cntc,
                                                const uint32_t* __restrict__ hist0,
                                                const uint32_t* __restrict__ hist1,
                                                const uint32_t* __restrict__ hist2,
                                                NmsState* st) {
  __shared__ unsigned long long ls[KPRE];
  __shared__ uint32_t lcnt, sp24, sneed;
  int tid = threadIdx.x;
  if (tid < 64) {
    uint32_t b1, nd1, b2, nd2, b3, nd3;
    wave_bucket(hist0, KPRE, &b1, &nd1);
    wave_bucket(hist1, nd1, &b2, &nd2);
    wave_bucket(hist2, nd2, &b3, &nd3);
    if (tid == 0) { sp24 = (b1 << 16) | (b2 << 8) | b3; sneed = nd3; lcnt = 0; }
  }
  __syncthreads();
  uint32_t p24 = sp24, need = sneed;
  // interleaved: lane -> segment, wave-index -> offset; all 1024 threads load in parallel
  int seg = tid & 63;
  uint32_t n = min(cntc[seg * CSTR], (uint32_t)SEGC);
  const unsigned long long* src = cand + (size_t)seg * SEGC;
  for (uint32_t i = (uint32_t)(tid >> 6); i < n; i += 16) {
    unsigned long long key = src[i];
    wave_compact((uint32_t)(key >> 40) == p24, key, &lcnt, ls, (uint32_t)KPRE);
  }
  __syncthreads();
  uint32_t cnum = min(lcnt, (uint32_t)KPRE);
  unsigned long long k0 = (tid < (int)cnum) ? ls[tid] : ~0ull;
  unsigned long long k1 = (tid + 1024 < (int)cnum) ? ls[tid + 1024] : ~0ull;
  unsigned long long k2 = (tid + 2048 < (int)cnum) ? ls[tid + 2048] : ~0ull;
  unsigned long long k3 = (tid + 3072 < (int)cnum) ? ls[tid + 3072] : ~0ull;
  uint32_t r0 = 0, r1 = 0, r2 = 0, r3 = 0;
  for (uint32_t p = 0; p < cnum; ++p) {
    unsigned long long kp = ls[p];
    r0 += (kp < k0); r1 += (kp < k1); r2 += (kp < k2); r3 += (kp < k3);
  }
  if (tid < (int)cnum && r0 == need - 1) st->pivot = k0;
  if (tid + 1024 < (int)cnum && r1 == need - 1) st->pivot = k1;
  if (tid + 2048 < (int)cnum && r2 == need - 1) st->pivot = k2;
  if (tid + 3072 < (int)cnum && r3 == need - 1) st->pivot = k3;
}

// select all keys <= pivot from cand segment blockIdx.x (exactly 4096 total)
__global__ void k_select(const unsigned long long* __restrict__ cand,
                         const uint32_t* __restrict__ cntc,
                         const NmsState* __restrict__ st,
                         unsigned long long* __restrict__ sel,
                         uint32_t* __restrict__ cnts) {
  int seg = blockIdx.x;
  uint32_t n = cntc[seg * CSTR]; if (n > SEGC) n = SEGC;
  unsigned long long piv = st->pivot;
  uint32_t* ctr = cnts + seg * CSTR;
  unsigned long long* buf = sel + (size_t)seg * SEG2;
  const unsigned long long* src = cand + (size_t)seg * SEGC;
  for (uint32_t i = threadIdx.x; i < n; i += blockDim.x) {
    unsigned long long key = src[i];
    wave_compact(key <= piv, key, ctr, buf, SEG2);
  }
}

// gather boxes/labels/values for the UNSORTED 4096 (segment-prefix slot order); stash keys
__global__ void __launch_bounds__(1024) k_gather(
    const unsigned long long* __restrict__ sel, const uint32_t* __restrict__ cnts,
    const float* __restrict__ boxes, const uint8_t* __restrict__ labs,
    float* __restrict__ x1a, float* __restrict__ y1a,
    float* __restrict__ x2a, float* __restrict__ y2a,
    float* __restrict__ vala, int* __restrict__ laba,
    unsigned long long* __restrict__ skeys, unsigned long long* __restrict__ vmask) {
  __shared__ uint32_t offs[NSEG + 1];
  int tid = threadIdx.x;
  if (tid < 64) {
    uint32_t c = min(cnts[tid * CSTR], (uint32_t)SEG2);
    uint32_t p = c;
    #pragma unroll
    for (int d = 1; d < 64; d <<= 1) {
      uint32_t v = __shfl_up(p, d, 64);
      if (tid >= d) p += v;
    }
    offs[tid] = p - c;
    if (tid == 63) offs[64] = p;
  }
  __syncthreads();
  int t = blockIdx.x * 1024 + tid;
  if (t >= KPRE) return;
  uint32_t total = offs[NSEG];
  unsigned long long key = ~0ull;
  if (t < (int)total) {
    int g = 0;
    while (t >= (int)offs[g + 1]) ++g;
    key = sel[(size_t)g * SEG2 + (t - offs[g])];
  }
  uint32_t idx = (uint32_t)key;
  if (idx >= NBOX) idx = 0;  // safety
  uint32_t u = (uint32_t)(key >> 32);
  float val = ord2f(~u);
  x1a[t] = boxes[idx];
  y1a[t] = boxes[(size_t)NBOX + idx];
  x2a[t] = boxes[(size_t)2 * NBOX + idx];
  y2a[t] = boxes[(size_t)3 * NBOX + idx];
  vala[t] = val;
  laba[t] = (int)labs[idx];
  skeys[t] = key;
  if (val >= 0.1f) atomicOr(&vmask[t >> 6], 1ull << (t & 63));
}

// sparse suppression pairs: directed (suppressor<<16)|suppressed, direction by key order
__global__ void k_pairs(const float* __restrict__ x1a, const float* __restrict__ y1a,
                        const float* __restrict__ x2a, const float* __restrict__ y2a,
                        const unsigned long long* __restrict__ skeys,
                        uint32_t* __restrict__ pcnt, uint32_t* __restrict__ pairs) {
#pragma clang fp contract(off)
  int bx = blockIdx.x, by = blockIdx.y;
  if (bx < by) return;
  int t = threadIdx.x;  // 64 threads
  int i = by * 64 + t;
  __shared__ float sx1[64], sy1[64], sx2[64], sy2[64], sar[64];
  __shared__ unsigned long long sk[64];
  int j0 = bx * 64 + t;
  float cx1 = x1a[j0], cy1 = y1a[j0], cx2 = x2a[j0], cy2 = y2a[j0];
  sx1[t] = cx1; sy1[t] = cy1; sx2[t] = cx2; sy2[t] = cy2;
  sar[t] = fmaxf(cx2 - cx1, 0.0f) * fmaxf(cy2 - cy1, 0.0f);
  sk[t] = skeys[j0];
  __syncthreads();
  float x1i = x1a[i], y1i = y1a[i], x2i = x2a[i], y2i = y2a[i];
  unsigned long long rk = skeys[i];
  float ari = fmaxf(x2i - x1i, 0.0f) * fmaxf(y2i - y1i, 0.0f);
  unsigned long long w = 0ull;
  #pragma unroll 8
  for (int jj = 0; jj < 64; ++jj) {
    int j = bx * 64 + jj;
    float iw = fmaxf(fminf(x2i, sx2[jj]) - fmaxf(x1i, sx1[jj]), 0.0f);
    float ih = fmaxf(fminf(y2i, sy2[jj]) - fmaxf(y1i, sy1[jj]), 0.0f);
    float inter = iw * ih;
    float den = ((ari + sar[jj]) - inter) + 1e-8f;  // exact ref op order
    float iou = inter / den;
    if ((iou > 0.5f) && (j > i)) w |= (1ull << jj);
  }
  int seg = (by * 64 + bx) & (NSEG - 1);
  uint32_t* ctr = pcnt + seg * CSTR;
  uint32_t* buf = pairs + (size_t)seg * PSEG;
  while (__ballot(w != 0ull)) {
    bool tk = (w != 0ull);
    uint32_t pr = 0;
    if (tk) {
      int b = __builtin_ctzll(w); w &= w - 1;
      int j = bx * 64 + b;
      bool i_sup = (rk < sk[b]);  // smaller key (higher score / lower orig idx) suppresses
      pr = i_sup ? (((uint32_t)i << 16) | (uint32_t)j)
                 : (((uint32_t)j << 16) | (uint32_t)i);
    }
    wave_compact32(tk, pr, ctr, buf, PSEG);
  }
}

// Jacobi fixpoint of A[i] = V[i] & forall (j->i) in E: !A[j]  (== greedy NMS result),
// then top-500-of-survivors select (radix narrowing) + rank emit.
__global__ void __launch_bounds__(1024) k_fix(
    const uint32_t* __restrict__ pcnt, const uint32_t* __restrict__ pairs,
    const unsigned long long* __restrict__ vmask, const unsigned long long* __restrict__ skeys,
    const float* __restrict__ x1a, const float* __restrict__ y1a,
    const float* __restrict__ x2a, const float* __restrict__ y2a,
    const float* __restrict__ vala, const int* __restrict__ laba,
    float* __restrict__ out) {
  __shared__ uint32_t lp[LCAP];
  __shared__ unsigned long long lk[KPRE];
  __shared__ uint32_t soff[NSEG + 1];
  __shared__ unsigned long long validm[64], accm[64];
  __shared__ uint32_t supp[128];
  __shared__ uint32_t chg, use_lds;
  __shared__ uint32_t orlo, orhi, andlo, andhi;
  __shared__ unsigned long long spre;
  __shared__ uint32_t sneed, scnt2;
  __shared__ uint32_t hsel[256];
  __shared__ uint32_t lsel[512];
  __shared__ unsigned long long kkbuf[512];
  int tid = threadIdx.x;

  for (int t = tid; t < KPOST * 6; t += 1024) out[t] = 0.0f;

  // wave-prefix soff over per-segment pair counts
  if (tid < 64) {
    uint32_t c = min(pcnt[tid * CSTR], (uint32_t)PSEG);
    uint32_t p = c;
    #pragma unroll
    for (int d = 1; d < 64; d <<= 1) {
      uint32_t v = __shfl_up(p, d, 64);
      if (tid >= d) p += v;
    }
    soff[tid] = p - c;
    if (tid == 63) { soff[64] = p; use_lds = (p <= (uint32_t)LCAP) ? 1u : 0u; }
    validm[tid] = vmask[tid];
    accm[tid] = vmask[tid];
  }
  for (int t = tid; t < KPRE; t += 1024) lk[t] = skeys[t];
  __syncthreads();
  uint32_t npair = soff[NSEG];
  if (use_lds) {
    // interleaved parallel load: lane=segment, wave-index=offset
    int seg = tid & 63;
    uint32_t c = soff[seg + 1] - soff[seg];
    uint32_t o = soff[seg];
    const uint32_t* src = pairs + (size_t)seg * PSEG;
    for (uint32_t off = (uint32_t)(tid >> 6); off < c; off += 16)
      lp[o + off] = src[off];
  }

  while (true) {
    __syncthreads();
    if (tid < 128) supp[tid] = 0;
    if (tid == 0) chg = 0;
    __syncthreads();
    if (use_lds) {
      for (uint32_t p = tid; p < npair; p += 1024) {
        uint32_t pr = lp[p];
        uint32_t i = pr >> 16, j = pr & 0xffffu;
        if ((accm[i >> 6] >> (i & 63)) & 1ull) atomicOr(&supp[j >> 5], 1u << (j & 31));
      }
    } else {
      int seg = tid & 63;
      uint32_t c = soff[seg + 1] - soff[seg];
      const uint32_t* src = pairs + (size_t)seg * PSEG;
      for (uint32_t off = (uint32_t)(tid >> 6); off < c; off += 16) {
        uint32_t pr = src[off];
        uint32_t i = pr >> 16, j = pr & 0xffffu;
        if ((accm[i >> 6] >> (i & 63)) & 1ull) atomicOr(&supp[j >> 5], 1u << (j & 31));
      }
    }
    __syncthreads();
    if (tid < 64) {
      unsigned long long s = ((unsigned long long)supp[2 * tid + 1] << 32) | supp[2 * tid];
      unsigned long long na = validm[tid] & ~s;
      if (na != accm[tid]) { accm[tid] = na; atomicOr(&chg, 1u); }
    }
    __syncthreads();
    if (chg == 0) break;
  }

  // ---- top-KPOST of survivors by key (diff-guided radix narrowing) ----
  if (tid == 0) {
    uint32_t ns = 0;
    for (int l = 0; l < 64; ++l) ns += (uint32_t)__builtin_popcountll(accm[l]);
    sneed = (ns < (uint32_t)KPOST) ? ns : (uint32_t)KPOST;
    orlo = 0; orhi = 0; andlo = ~0u; andhi = ~0u; scnt2 = 0;
  }
  __syncthreads();
  uint32_t need0 = sneed;
  if (need0 == 0) return;

  for (int t = tid; t < KPRE; t += 1024) {
    if ((accm[t >> 6] >> (t & 63)) & 1ull) {
      unsigned long long k = lk[t];
      atomicOr(&orlo, (uint32_t)k); atomicOr(&orhi, (uint32_t)(k >> 32));
      atomicAnd(&andlo, (uint32_t)k); atomicAnd(&andhi, (uint32_t)(k >> 32));
    }
  }
  __syncthreads();
  unsigned long long vor = ((unsigned long long)orhi << 32) | orlo;
  unsigned long long vand = ((unsigned long long)andhi << 32) | andlo;
  unsigned long long diff = vor ^ vand;
  unsigned long long pre = 0;
  uint32_t need = need0;
  for (int b = 7; b >= 0; --b) {
    uint32_t db = (uint32_t)(diff >> (8 * b)) & 255u;
    if (db == 0) { pre = (pre << 8) | ((uint32_t)(vand >> (8 * b)) & 255u); continue; }
    if (tid < 256) hsel[tid] = 0;
    __syncthreads();
    for (int t = tid; t < KPRE; t += 1024) {
      if ((accm[t >> 6] >> (t & 63)) & 1ull) {
        unsigned long long k = lk[t];
        bool pm = (b == 7) ? true : ((k >> (8 * b + 8)) == pre);
        if (pm) atomicAdd(&hsel[(uint32_t)(k >> (8 * b)) & 255u], 1u);
      }
    }
    __syncthreads();
    if (tid < 64) {
      uint32_t c0 = hsel[4 * tid], c1 = hsel[4 * tid + 1],
               c2 = hsel[4 * tid + 2], c3 = hsel[4 * tid + 3];
      uint32_t s = c0 + c1 + c2 + c3;
      uint32_t p = s;
      #pragma unroll
      for (int d = 1; d < 64; d <<= 1) {
        uint32_t v = __shfl_up(p, d, 64);
        if (tid >= d) p += v;
      }
      uint32_t e0 = p - s, e1 = e0 + c0, e2 = e1 + c1, e3 = e2 + c2, e4 = e3 + c3;
      uint32_t eb[5] = {e0, e1, e2, e3, e4};
      #pragma unroll
      for (int q = 0; q < 4; ++q) {
        if (eb[q] < need && need <= eb[q + 1]) {
          spre = (pre << 8) | (uint32_t)(4 * tid + q);
          sneed = need - eb[q];
        }
      }
    }
    __syncthreads();
    pre = spre; need = sneed;
    __syncthreads();
  }
  unsigned long long T = pre;  // exact key of the need0-th smallest survivor

  for (int t = tid; t < KPRE; t += 1024) {
    bool take = ((accm[t >> 6] >> (t & 63)) & 1ull) && (lk[t] <= T);
    wave_compact32(take, (uint32_t)t, &scnt2, lsel, 512u);
  }
  __syncthreads();
  uint32_t cnt = min(scnt2, 512u);
  if (tid < (int)cnt) kkbuf[tid] = lk[lsel[tid]];
  __syncthreads();
  if (tid < (int)cnt) {
    unsigned long long k0 = kkbuf[tid];
    uint32_t rank = 0;
    for (uint32_t p = 0; p < cnt; ++p) rank += (kkbuf[p] < k0) ? 1u : 0u;
    if (rank < (uint32_t)KPOST) {
      int i = (int)lsel[tid];
      out[rank * 6 + 0] = x1a[i];
      out[rank * 6 + 1] = y1a[i];
      out[rank * 6 + 2] = x2a[i];
      out[rank * 6 + 3] = y2a[i];
      out[rank * 6 + 4] = vala[i];
      out[rank * 6 + 5] = (float)laba[i];
    }
  }
}

extern "C" void kernel_launch(void* const* d_in, const int* in_sizes, int n_in,
                              void* d_out, int out_size, void* d_ws, size_t ws_size,
                              hipStream_t stream) {
  const float* boxes = (const float*)d_in[0];
  const float* cls   = (const float*)d_in[1];
  float* out = (float*)d_out;
  char* ws = (char*)d_ws;

  uint32_t* keys = (uint32_t*)(ws + OFF_KEYS);
  unsigned long long* cand  = (unsigned long long*)(ws + OFF_CAND);
  unsigned long long* sel   = (unsigned long long*)(ws + OFF_SEL);
  unsigned long long* skeys = (unsigned long long*)(ws + OFF_SKEYS);
  uint32_t* pairs = (uint32_t*)(ws + OFF_PAIRS);
  unsigned long long* vmask = (unsigned long long*)(ws + OFF_VMASK);
  uint32_t* hist = (uint32_t*)(ws + OFF_HIST);
  uint32_t* cnts = (uint32_t*)(ws + OFF_CNTS);
  uint32_t* cntc  = cnts;                    // cand counters
  uint32_t* cnts3 = cnts + NSEG * CSTR;      // sel counters
  uint32_t* pcnt  = cnts + 2 * NSEG * CSTR;  // pair counters
  NmsState* st = (NmsState*)(ws + OFF_STATE);
  float* x1a = (float*)(ws + OFF_ARR);
  float* y1a = x1a + KPRE;
  float* x2a = y1a + KPRE;
  float* y2a = x2a + KPRE;
  float* vala = y2a + KPRE;
  int*   laba = (int*)(vala + KPRE);
  uint8_t* labs = (uint8_t*)(ws + OFF_LAB);

  k_zero<<<1, 256, 0, stream>>>(hist, st, vmask, cnts);
  k_score<<<1024, 256, 0, stream>>>(cls, keys, labs, hist);
  k_hist1<<<1024, 256, 0, stream>>>(keys, hist, hist + 256);
  k_compact_hist2<<<1024, 256, 0, stream>>>(keys, hist, hist + 256, hist + 512, cand, cntc);
  k_pivot<<<1, 1024, 0, stream>>>(cand, cntc, hist, hist + 256, hist + 512, st);
  k_select<<<NSEG, 256, 0, stream>>>(cand, cntc, st, sel, cnts3);
  k_gather<<<4, 1024, 0, stream>>>(sel, cnts3, boxes, labs, x1a, y1a, x2a, y2a,
                                   vala, laba, skeys, vmask);
  k_pairs<<<dim3(64, 64), 64, 0, stream>>>(x1a, y1a, x2a, y2a, skeys, pcnt, pairs);
  k_fix<<<1, 1024, 0, stream>>>(pcnt, pairs, vmask, skeys, x1a, y1a, x2a, y2a,
                                vala, laba, out);
}

// Round 9
// 314.902 us; speedup vs baseline: 1.4463x; 1.1531x over previous
//
#include <hip/hip_runtime.h>
#include <stdint.h>

#define NBOX 2000000
#define NCLS 10
#define KPRE 4096
#define KPOST 500
#define NSEG 64
#define SEGC 4096   // cand per-segment cap
#define SEG2 1024   // sel per-segment cap
#define PSEG 2048   // pairs per-segment cap
#define LCAP 16384  // LDS pair cache (64 KB)
#define CSTR 16     // counter stride in u32 (one 64B cacheline per counter)

// ---- workspace layout (bytes) ----
#define OFF_KEYS   ((size_t)0)                               // NBOX*4 (u32 ord; idx implicit)
#define OFF_CAND   ((size_t)8000000)
#define OFF_SEL    (OFF_CAND  + (size_t)NSEG * SEGC * 8)
#define OFF_SKEYS  (OFF_SEL   + (size_t)NSEG * SEG2 * 8)
#define OFF_PAIRS  (OFF_SKEYS + (size_t)KPRE * 8)
#define OFF_VMASK  (OFF_PAIRS + (size_t)NSEG * PSEG * 4)
#define OFF_HIST   (OFF_VMASK + (size_t)64 * 8)
#define OFF_CNTS   (OFF_HIST  + (size_t)768 * 4)             // 3*64 counters, 64B stride
#define OFF_STATE  (OFF_CNTS  + (size_t)3 * NSEG * CSTR * 4)
#define OFF_ARR    (OFF_STATE + (size_t)64)
#define OFF_LAB    (OFF_ARR   + (size_t)KPRE * 24)           // NBOX u8 labels
#define ZERO_BYTES ((size_t)(64 * 8 + 768 * 4 + 3 * NSEG * CSTR * 4 + 64))  // vmask..state

struct NmsState {
  unsigned long long pivot;
  unsigned long long pad[7];
};

__device__ __forceinline__ uint32_t f2ord(float f) {
  uint32_t b = __float_as_uint(f);
  return (b & 0x80000000u) ? ~b : (b | 0x80000000u);
}
__device__ __forceinline__ float ord2f(uint32_t ord) {
  uint32_t b = (ord & 0x80000000u) ? (ord ^ 0x80000000u) : ~ord;
  return __uint_as_float(b);
}

__device__ __forceinline__ unsigned long long shflx64(unsigned long long v, int mask) {
  union { unsigned long long u; int i[2]; } a; a.u = v;
  a.i[0] = __shfl_xor(a.i[0], mask, 64);
  a.i[1] = __shfl_xor(a.i[1], mask, 64);
  return a.u;
}

// executed by one FULL wave (lanes 0..63): bucket of the need-th smallest in h[256]
__device__ __forceinline__ void wave_bucket(const uint32_t* __restrict__ h, uint32_t need,
                                            uint32_t* bin_out, uint32_t* nd_out) {
  int l = threadIdx.x & 63;
  uint4 h4 = reinterpret_cast<const uint4*>(h)[l];
  uint32_t s = h4.x + h4.y + h4.z + h4.w;
  uint32_t p = s;
  #pragma unroll
  for (int d = 1; d < 64; d <<= 1) {
    uint32_t v = __shfl_up(p, d, 64);
    if (l >= d) p += v;
  }
  uint32_t e0 = p - s, e1 = e0 + h4.x, e2 = e1 + h4.y, e3 = e2 + h4.z, e4 = e3 + h4.w;
  uint32_t eb[5] = {e0, e1, e2, e3, e4};
  uint32_t bin = 0xFFFFFFFFu, nd = 1;
  #pragma unroll
  for (int q = 0; q < 4; ++q)
    if (eb[q] < need && need <= eb[q + 1]) { bin = (uint32_t)(4 * l + q); nd = need - eb[q]; }
  unsigned long long mm = __ballot(bin != 0xFFFFFFFFu);
  int src = mm ? __builtin_ctzll(mm) : 0;
  *bin_out = (uint32_t)__shfl((int)bin, src);
  *nd_out  = (uint32_t)__shfl((int)nd, src);
}

// wave-aggregated LDS histogram add — fast when bins are near-uniform within the wave
__device__ __forceinline__ void hist_add_wave(uint32_t* lh, uint32_t bin) {
  unsigned long long act = __ballot(1);
  int lane = threadIdx.x & 63;
  unsigned long long rem = act;
  while (rem) {
    int leader = __builtin_ctzll(rem);
    uint32_t lb = __shfl(bin, leader);
    unsigned long long same = __ballot(bin == lb) & act;
    if (lane == leader) atomicAdd(&lh[lb], (uint32_t)__builtin_popcountll(same));
    rem &= ~same;
  }
}

// wave-aggregated compaction (u64 payload): one atomic per wave; works with partial masks
__device__ __forceinline__ void wave_compact(bool take, unsigned long long key,
                                             uint32_t* counter, unsigned long long* buf,
                                             uint32_t cap) {
  unsigned long long mm = __ballot(take);
  if (take) {
    int lane = threadIdx.x & 63;
    unsigned long long lt = (lane == 0) ? 0ull : (~0ull >> (64 - lane));
    int rank = __builtin_popcountll(mm & lt);
    int leader = __builtin_ctzll(mm);
    uint32_t base = 0;
    if (rank == 0) base = atomicAdd(counter, (uint32_t)__builtin_popcountll(mm));
    base = __shfl(base, leader);
    uint32_t pos = base + (uint32_t)rank;
    if (pos < cap) buf[pos] = key;
  }
}

// wave-aggregated compaction (u32 payload)
__device__ __forceinline__ void wave_compact32(bool take, uint32_t key,
                                               uint32_t* counter, uint32_t* buf,
                                               uint32_t cap) {
  unsigned long long mm = __ballot(take);
  if (take) {
    int lane = threadIdx.x & 63;
    unsigned long long lt = (lane == 0) ? 0ull : (~0ull >> (64 - lane));
    int rank = __builtin_popcountll(mm & lt);
    int leader = __builtin_ctzll(mm);
    uint32_t base = 0;
    if (rank == 0) base = atomicAdd(counter, (uint32_t)__builtin_popcountll(mm));
    base = __shfl(base, leader);
    uint32_t pos = base + (uint32_t)rank;
    if (pos < cap) buf[pos] = key;
  }
}

// ---------------- kernels ----------------

// scores (max over classes) -> u32 ord keys + per-box argmax label + byte0 histogram
__global__ void k_score(const float* __restrict__ cls, uint32_t* __restrict__ keys,
                        uint8_t* __restrict__ labs, uint32_t* __restrict__ hist0) {
  __shared__ uint32_t lh[256];
  for (int i = threadIdx.x; i < 256; i += blockDim.x) lh[i] = 0;
  __syncthreads();
  const int nvec = NBOX / 4;
  for (int v = blockIdx.x * blockDim.x + threadIdx.x; v < nvec; v += gridDim.x * blockDim.x) {
    float4 m = reinterpret_cast<const float4*>(cls)[v];
    int lx = 0, ly = 0, lz = 0, lw = 0;
    #pragma unroll
    for (int c = 1; c < NCLS; ++c) {
      float4 x = reinterpret_cast<const float4*>(cls + (size_t)c * NBOX)[v];
      if (x.x > m.x) { m.x = x.x; lx = c; }
      if (x.y > m.y) { m.y = x.y; ly = c; }
      if (x.z > m.z) { m.z = x.z; lz = c; }
      if (x.w > m.w) { m.w = x.w; lw = c; }
    }
    float s[4] = {m.x, m.y, m.z, m.w};
    uint32_t u4[4];
    #pragma unroll
    for (int q = 0; q < 4; ++q) {
      float ms = (s[q] >= 0.1f) ? s[q] : -1.0f;
      uint32_t u = ~f2ord(ms);
      u4[q] = u;
      hist_add_wave(lh, u >> 24);   // bins near-constant (byte0) -> 1-2 iters
    }
    reinterpret_cast<uint4*>(keys)[v] = make_uint4(u4[0], u4[1], u4[2], u4[3]);
    uchar4 lb; lb.x = (uint8_t)lx; lb.y = (uint8_t)ly; lb.z = (uint8_t)lz; lb.w = (uint8_t)lw;
    reinterpret_cast<uchar4*>(labs)[v] = lb;
  }
  __syncthreads();
  for (int i = threadIdx.x; i < 256; i += blockDim.x)
    if (lh[i]) atomicAdd(&hist0[i], lh[i]);
}

// byte1 histogram among byte0==b1 (b1 from inline wave-parallel bucket find)
__global__ void k_hist1(const uint32_t* __restrict__ keys,
                        const uint32_t* __restrict__ hist0, uint32_t* __restrict__ hist1) {
  __shared__ uint32_t lh[256];
  __shared__ uint32_t sb1;
  if (threadIdx.x < 64) {
    uint32_t b1, nd1;
    wave_bucket(hist0, KPRE, &b1, &nd1);
    if (threadIdx.x == 0) sb1 = b1;
  }
  for (int i = threadIdx.x; i < 256; i += blockDim.x) lh[i] = 0;
  __syncthreads();
  uint32_t b1 = sb1;
  for (int i = blockIdx.x * blockDim.x + threadIdx.x; i < NBOX; i += gridDim.x * blockDim.x) {
    uint32_t u = keys[i];
    if ((u >> 24) == b1) atomicAdd(&lh[(u >> 16) & 0xffu], 1u);
  }
  __syncthreads();
  for (int i = threadIdx.x; i < 256; i += blockDim.x)
    if (lh[i]) atomicAdd(&hist1[i], lh[i]);
}

// compact all keys with top16 <= p16 into segment blockIdx&63; byte2 histogram
__global__ void k_compact_hist2(const uint32_t* __restrict__ keys,
                                const uint32_t* __restrict__ hist0,
                                const uint32_t* __restrict__ hist1,
                                uint32_t* __restrict__ hist2,
                                unsigned long long* __restrict__ cand,
                                uint32_t* __restrict__ cntc) {
  __shared__ uint32_t lh[256];
  __shared__ uint32_t sp16;
  if (threadIdx.x < 64) {
    uint32_t b1, nd1, b2, nd2;
    wave_bucket(hist0, KPRE, &b1, &nd1);
    wave_bucket(hist1, nd1, &b2, &nd2);
    if (threadIdx.x == 0) sp16 = (b1 << 8) | b2;
  }
  for (int i = threadIdx.x; i < 256; i += blockDim.x) lh[i] = 0;
  __syncthreads();
  uint32_t p16 = sp16;
  int seg = blockIdx.x & (NSEG - 1);
  uint32_t* ctr = cntc + seg * CSTR;
  unsigned long long* buf = cand + (size_t)seg * SEGC;
  for (int i = blockIdx.x * blockDim.x + threadIdx.x; i < NBOX; i += gridDim.x * blockDim.x) {
    uint32_t u = keys[i];
    uint32_t pref = u >> 16;
    bool take = (pref <= p16);
    unsigned long long key = ((unsigned long long)u << 32) | (uint32_t)i;
    wave_compact(take, key, ctr, buf, SEGC);
    if (take && pref == p16) atomicAdd(&lh[(u >> 8) & 0xffu], 1u);
  }
  __syncthreads();
  for (int i = threadIdx.x; i < 256; i += blockDim.x)
    if (lh[i]) atomicAdd(&hist2[i], lh[i]);
}

// pivot = need3-th smallest key of the 24-bit-exact bucket.
// Coalesced wave-per-segment scan, LDS compact, batched rank-select.
__global__ void __launch_bounds__(1024) k_pivot(const unsigned long long* __restrict__ cand,
                                                const uint32_t* __restrict__ cntc,
                                                const uint32_t* __restrict__ hist0,
                                                const uint32_t* __restrict__ hist1,
                                                const uint32_t* __restrict__ hist2,
                                                NmsState* st) {
  __shared__ unsigned long long ls[KPRE];
  __shared__ uint32_t lcnt, sp24, sneed;
  int tid = threadIdx.x;
  int wid = tid >> 6, lane = tid & 63;
  if (tid < 64) {
    uint32_t b1, nd1, b2, nd2, b3, nd3;
    wave_bucket(hist0, KPRE, &b1, &nd1);
    wave_bucket(hist1, nd1, &b2, &nd2);
    wave_bucket(hist2, nd2, &b3, &nd3);
    if (tid == 0) { sp24 = (b1 << 16) | (b2 << 8) | b3; sneed = nd3; lcnt = 0; }
  }
  __syncthreads();
  uint32_t p24 = sp24, need = sneed;
  // coalesced: wave w scans segments w, w+16, ... ; lanes consecutive within segment
  for (int g = wid; g < NSEG; g += 16) {
    uint32_t n = min(cntc[g * CSTR], (uint32_t)SEGC);
    const unsigned long long* src = cand + (size_t)g * SEGC;
    for (uint32_t i = (uint32_t)lane; i < n; i += 64) {
      unsigned long long key = src[i];
      wave_compact((uint32_t)(key >> 40) == p24, key, &lcnt, ls, (uint32_t)KPRE);
    }
  }
  __syncthreads();
  uint32_t cnum = min(lcnt, (uint32_t)KPRE);
  unsigned long long k0 = (tid < (int)cnum) ? ls[tid] : ~0ull;
  unsigned long long k1 = (tid + 1024 < (int)cnum) ? ls[tid + 1024] : ~0ull;
  unsigned long long k2 = (tid + 2048 < (int)cnum) ? ls[tid + 2048] : ~0ull;
  unsigned long long k3 = (tid + 3072 < (int)cnum) ? ls[tid + 3072] : ~0ull;
  uint32_t r0 = 0, r1 = 0, r2 = 0, r3 = 0;
  #pragma unroll 8
  for (uint32_t p = 0; p < cnum; ++p) {
    unsigned long long kp = ls[p];
    r0 += (kp < k0); r1 += (kp < k1); r2 += (kp < k2); r3 += (kp < k3);
  }
  if (tid < (int)cnum && r0 == need - 1) st->pivot = k0;
  if (tid + 1024 < (int)cnum && r1 == need - 1) st->pivot = k1;
  if (tid + 2048 < (int)cnum && r2 == need - 1) st->pivot = k2;
  if (tid + 3072 < (int)cnum && r3 == need - 1) st->pivot = k3;
}

// select all keys <= pivot from cand segment blockIdx.x (exactly 4096 total)
__global__ void k_select(const unsigned long long* __restrict__ cand,
                         const uint32_t* __restrict__ cntc,
                         const NmsState* __restrict__ st,
                         unsigned long long* __restrict__ sel,
                         uint32_t* __restrict__ cnts) {
  int seg = blockIdx.x;
  uint32_t n = cntc[seg * CSTR]; if (n > SEGC) n = SEGC;
  unsigned long long piv = st->pivot;
  uint32_t* ctr = cnts + seg * CSTR;
  unsigned long long* buf = sel + (size_t)seg * SEG2;
  const unsigned long long* src = cand + (size_t)seg * SEGC;
  for (uint32_t i = threadIdx.x; i < n; i += blockDim.x) {
    unsigned long long key = src[i];
    wave_compact(key <= piv, key, ctr, buf, SEG2);
  }
}

// gather boxes/labels/values for the UNSORTED 4096 (segment-prefix slot order); stash keys
__global__ void __launch_bounds__(1024) k_gather(
    const unsigned long long* __restrict__ sel, const uint32_t* __restrict__ cnts,
    const float* __restrict__ boxes, const uint8_t* __restrict__ labs,
    float* __restrict__ x1a, float* __restrict__ y1a,
    float* __restrict__ x2a, float* __restrict__ y2a,
    float* __restrict__ vala, int* __restrict__ laba,
    unsigned long long* __restrict__ skeys, unsigned long long* __restrict__ vmask) {
  __shared__ uint32_t offs[NSEG + 1];
  int tid = threadIdx.x;
  if (tid < 64) {
    uint32_t c = min(cnts[tid * CSTR], (uint32_t)SEG2);
    uint32_t p = c;
    #pragma unroll
    for (int d = 1; d < 64; d <<= 1) {
      uint32_t v = __shfl_up(p, d, 64);
      if (tid >= d) p += v;
    }
    offs[tid] = p - c;
    if (tid == 63) offs[64] = p;
  }
  __syncthreads();
  int t = blockIdx.x * 1024 + tid;
  if (t >= KPRE) return;
  uint32_t total = offs[NSEG];
  unsigned long long key = ~0ull;
  if (t < (int)total) {
    int g = 0;
    while (t >= (int)offs[g + 1]) ++g;
    key = sel[(size_t)g * SEG2 + (t - offs[g])];
  }
  uint32_t idx = (uint32_t)key;
  if (idx >= NBOX) idx = 0;  // safety
  uint32_t u = (uint32_t)(key >> 32);
  float val = ord2f(~u);
  x1a[t] = boxes[idx];
  y1a[t] = boxes[(size_t)NBOX + idx];
  x2a[t] = boxes[(size_t)2 * NBOX + idx];
  y2a[t] = boxes[(size_t)3 * NBOX + idx];
  vala[t] = val;
  laba[t] = (int)labs[idx];
  skeys[t] = key;
  if (val >= 0.1f) atomicOr(&vmask[t >> 6], 1ull << (t & 63));
}

// sparse suppression pairs: directed (suppressor<<16)|suppressed, direction by key order
__global__ void k_pairs(const float* __restrict__ x1a, const float* __restrict__ y1a,
                        const float* __restrict__ x2a, const float* __restrict__ y2a,
                        const unsigned long long* __restrict__ skeys,
                        uint32_t* __restrict__ pcnt, uint32_t* __restrict__ pairs) {
#pragma clang fp contract(off)
  int bx = blockIdx.x, by = blockIdx.y;
  if (bx < by) return;
  int t = threadIdx.x;  // 64 threads
  int i = by * 64 + t;
  __shared__ float sx1[64], sy1[64], sx2[64], sy2[64], sar[64];
  __shared__ unsigned long long sk[64];
  int j0 = bx * 64 + t;
  float cx1 = x1a[j0], cy1 = y1a[j0], cx2 = x2a[j0], cy2 = y2a[j0];
  sx1[t] = cx1; sy1[t] = cy1; sx2[t] = cx2; sy2[t] = cy2;
  sar[t] = fmaxf(cx2 - cx1, 0.0f) * fmaxf(cy2 - cy1, 0.0f);
  sk[t] = skeys[j0];
  __syncthreads();
  float x1i = x1a[i], y1i = y1a[i], x2i = x2a[i], y2i = y2a[i];
  unsigned long long rk = skeys[i];
  float ari = fmaxf(x2i - x1i, 0.0f) * fmaxf(y2i - y1i, 0.0f);
  unsigned long long w = 0ull;
  #pragma unroll 8
  for (int jj = 0; jj < 64; ++jj) {
    int j = bx * 64 + jj;
    float iw = fmaxf(fminf(x2i, sx2[jj]) - fmaxf(x1i, sx1[jj]), 0.0f);
    float ih = fmaxf(fminf(y2i, sy2[jj]) - fmaxf(y1i, sy1[jj]), 0.0f);
    float inter = iw * ih;
    float den = ((ari + sar[jj]) - inter) + 1e-8f;  // exact ref op order
    float iou = inter / den;
    if ((iou > 0.5f) && (j > i)) w |= (1ull << jj);
  }
  int seg = (by * 64 + bx) & (NSEG - 1);
  uint32_t* ctr = pcnt + seg * CSTR;
  uint32_t* buf = pairs + (size_t)seg * PSEG;
  while (__ballot(w != 0ull)) {
    bool tk = (w != 0ull);
    uint32_t pr = 0;
    if (tk) {
      int b = __builtin_ctzll(w); w &= w - 1;
      int j = bx * 64 + b;
      bool i_sup = (rk < sk[b]);  // smaller key (higher score / lower orig idx) suppresses
      pr = i_sup ? (((uint32_t)i << 16) | (uint32_t)j)
                 : (((uint32_t)j << 16) | (uint32_t)i);
    }
    wave_compact32(tk, pr, ctr, buf, PSEG);
  }
}

// Jacobi fixpoint of A[i] = V[i] & forall (j->i) in E: !A[j]  (== greedy NMS result),
// then top-500-of-survivors select (radix narrowing) + rank emit.
__global__ void __launch_bounds__(1024) k_fix(
    const uint32_t* __restrict__ pcnt, const uint32_t* __restrict__ pairs,
    const unsigned long long* __restrict__ vmask, const unsigned long long* __restrict__ skeys,
    const float* __restrict__ x1a, const float* __restrict__ y1a,
    const float* __restrict__ x2a, const float* __restrict__ y2a,
    const float* __restrict__ vala, const int* __restrict__ laba,
    float* __restrict__ out) {
  __shared__ uint32_t lp[LCAP];
  __shared__ unsigned long long lk[KPRE];
  __shared__ uint32_t soff[NSEG + 1];
  __shared__ unsigned long long validm[64], accm[64];
  __shared__ uint32_t supp[128];
  __shared__ uint32_t chg, use_lds;
  __shared__ uint32_t orlo, orhi, andlo, andhi;
  __shared__ unsigned long long spre;
  __shared__ uint32_t sneed, scnt2;
  __shared__ uint32_t hsel[256];
  __shared__ uint32_t lsel[512];
  __shared__ unsigned long long kkbuf[512];
  int tid = threadIdx.x;
  int wid = tid >> 6, lane = tid & 63;

  for (int t = tid; t < KPOST * 6; t += 1024) out[t] = 0.0f;
  if (tid < 512) kkbuf[tid] = ~0ull;

  // wave-prefix soff over per-segment pair counts
  if (tid < 64) {
    uint32_t c = min(pcnt[tid * CSTR], (uint32_t)PSEG);
    uint32_t p = c;
    #pragma unroll
    for (int d = 1; d < 64; d <<= 1) {
      uint32_t v = __shfl_up(p, d, 64);
      if (tid >= d) p += v;
    }
    soff[tid] = p - c;
    if (tid == 63) { soff[64] = p; use_lds = (p <= (uint32_t)LCAP) ? 1u : 0u; }
    validm[tid] = vmask[tid];
    accm[tid] = vmask[tid];
  }
  for (int t = tid; t < KPRE; t += 1024) lk[t] = skeys[t];
  __syncthreads();
  uint32_t npair = soff[NSEG];
  if (use_lds) {
    // coalesced: wave w loads segments w, w+16, ... ; lanes consecutive within segment
    for (int g = wid; g < NSEG; g += 16) {
      uint32_t o = soff[g], c = soff[g + 1] - o;
      const uint32_t* src = pairs + (size_t)g * PSEG;
      for (uint32_t i = (uint32_t)lane; i < c; i += 64) lp[o + i] = src[i];
    }
  }

  while (true) {
    __syncthreads();
    if (tid < 128) supp[tid] = 0;
    if (tid == 0) chg = 0;
    __syncthreads();
    if (use_lds) {
      for (uint32_t p = tid; p < npair; p += 1024) {
        uint32_t pr = lp[p];
        uint32_t i = pr >> 16, j = pr & 0xffffu;
        if ((accm[i >> 6] >> (i & 63)) & 1ull) atomicOr(&supp[j >> 5], 1u << (j & 31));
      }
    } else {
      for (int g = wid; g < NSEG; g += 16) {
        uint32_t c = soff[g + 1] - soff[g];
        const uint32_t* src = pairs + (size_t)g * PSEG;
        for (uint32_t i = (uint32_t)lane; i < c; i += 64) {
          uint32_t pr = src[i];
          uint32_t ii = pr >> 16, j = pr & 0xffffu;
          if ((accm[ii >> 6] >> (ii & 63)) & 1ull) atomicOr(&supp[j >> 5], 1u << (j & 31));
        }
      }
    }
    __syncthreads();
    if (tid < 64) {
      unsigned long long s = ((unsigned long long)supp[2 * tid + 1] << 32) | supp[2 * tid];
      unsigned long long na = validm[tid] & ~s;
      if (na != accm[tid]) { accm[tid] = na; atomicOr(&chg, 1u); }
    }
    __syncthreads();
    if (chg == 0) break;
  }

  // ---- top-KPOST of survivors by key (diff-guided radix narrowing) ----
  if (tid == 0) {
    uint32_t ns = 0;
    for (int l = 0; l < 64; ++l) ns += (uint32_t)__builtin_popcountll(accm[l]);
    sneed = (ns < (uint32_t)KPOST) ? ns : (uint32_t)KPOST;
    orlo = 0; orhi = 0; andlo = ~0u; andhi = ~0u; scnt2 = 0;
  }
  __syncthreads();
  uint32_t need0 = sneed;
  if (need0 == 0) return;

  {
    unsigned long long myor = 0ull, myand = ~0ull;
    for (int t = tid; t < KPRE; t += 1024) {
      if ((accm[t >> 6] >> (t & 63)) & 1ull) {
        unsigned long long k = lk[t];
        myor |= k; myand &= k;
      }
    }
    #pragma unroll
    for (int d = 1; d < 64; d <<= 1) {
      myor |= shflx64(myor, d);
      myand &= shflx64(myand, d);
    }
    if (lane == 0) {
      atomicOr(&orlo, (uint32_t)myor); atomicOr(&orhi, (uint32_t)(myor >> 32));
      atomicAnd(&andlo, (uint32_t)myand); atomicAnd(&andhi, (uint32_t)(myand >> 32));
    }
  }
  __syncthreads();
  unsigned long long vor = ((unsigned long long)orhi << 32) | orlo;
  unsigned long long vand = ((unsigned long long)andhi << 32) | andlo;
  unsigned long long diff = vor ^ vand;
  unsigned long long pre = 0;
  uint32_t need = need0;
  for (int b = 7; b >= 0; --b) {
    uint32_t db = (uint32_t)(diff >> (8 * b)) & 255u;
    if (db == 0) { pre = (pre << 8) | ((uint32_t)(vand >> (8 * b)) & 255u); continue; }
    if (tid < 256) hsel[tid] = 0;
    __syncthreads();
    for (int t = tid; t < KPRE; t += 1024) {
      if ((accm[t >> 6] >> (t & 63)) & 1ull) {
        unsigned long long k = lk[t];
        bool pm = (b == 7) ? true : ((k >> (8 * b + 8)) == pre);
        if (pm) atomicAdd(&hsel[(uint32_t)(k >> (8 * b)) & 255u], 1u);
      }
    }
    __syncthreads();
    if (tid < 64) {
      uint32_t c0 = hsel[4 * tid], c1 = hsel[4 * tid + 1],
               c2 = hsel[4 * tid + 2], c3 = hsel[4 * tid + 3];
      uint32_t s = c0 + c1 + c2 + c3;
      uint32_t p = s;
      #pragma unroll
      for (int d = 1; d < 64; d <<= 1) {
        uint32_t v = __shfl_up(p, d, 64);
        if (tid >= d) p += v;
      }
      uint32_t e0 = p - s, e1 = e0 + c0, e2 = e1 + c1, e3 = e2 + c2, e4 = e3 + c3;
      uint32_t eb[5] = {e0, e1, e2, e3, e4};
      #pragma unroll
      for (int q = 0; q < 4; ++q) {
        if (eb[q] < need && need <= eb[q + 1]) {
          spre = (pre << 8) | (uint32_t)(4 * tid + q);
          sneed = need - eb[q];
        }
      }
    }
    __syncthreads();
    pre = spre; need = sneed;
    __syncthreads();
  }
  unsigned long long T = pre;  // exact key of the need0-th smallest survivor

  for (int t = tid; t < KPRE; t += 1024) {
    bool take = ((accm[t >> 6] >> (t & 63)) & 1ull) && (lk[t] <= T);
    wave_compact32(take, (uint32_t)t, &scnt2, lsel, 512u);
  }
  __syncthreads();
  uint32_t cnt = min(scnt2, 512u);
  if (tid < (int)cnt) kkbuf[tid] = lk[lsel[tid]];
  __syncthreads();
  if (tid < (int)cnt) {
    unsigned long long k0 = kkbuf[tid];
    uint32_t rank = 0;
    #pragma unroll 8
    for (uint32_t p = 0; p < 512u; ++p) rank += (kkbuf[p] < k0) ? 1u : 0u;  // padded ~0ull
    if (rank < (uint32_t)KPOST) {
      int i = (int)lsel[tid];
      out[rank * 6 + 0] = x1a[i];
      out[rank * 6 + 1] = y1a[i];
      out[rank * 6 + 2] = x2a[i];
      out[rank * 6 + 3] = y2a[i];
      out[rank * 6 + 4] = vala[i];
      out[rank * 6 + 5] = (float)laba[i];
    }
  }
}

extern "C" void kernel_launch(void* const* d_in, const int* in_sizes, int n_in,
                              void* d_out, int out_size, void* d_ws, size_t ws_size,
                              hipStream_t stream) {
  const float* boxes = (const float*)d_in[0];
  const float* cls   = (const float*)d_in[1];
  float* out = (float*)d_out;
  char* ws = (char*)d_ws;

  uint32_t* keys = (uint32_t*)(ws + OFF_KEYS);
  unsigned long long* cand  = (unsigned long long*)(ws + OFF_CAND);
  unsigned long long* sel   = (unsigned long long*)(ws + OFF_SEL);
  unsigned long long* skeys = (unsigned long long*)(ws + OFF_SKEYS);
  uint32_t* pairs = (uint32_t*)(ws + OFF_PAIRS);
  unsigned long long* vmask = (unsigned long long*)(ws + OFF_VMASK);
  uint32_t* hist = (uint32_t*)(ws + OFF_HIST);
  uint32_t* cnts = (uint32_t*)(ws + OFF_CNTS);
  uint32_t* cntc  = cnts;                    // cand counters
  uint32_t* cnts3 = cnts + NSEG * CSTR;      // sel counters
  uint32_t* pcnt  = cnts + 2 * NSEG * CSTR;  // pair counters
  NmsState* st = (NmsState*)(ws + OFF_STATE);
  float* x1a = (float*)(ws + OFF_ARR);
  float* y1a = x1a + KPRE;
  float* x2a = y1a + KPRE;
  float* y2a = x2a + KPRE;
  float* vala = y2a + KPRE;
  int*   laba = (int*)(vala + KPRE);
  uint8_t* labs = (uint8_t*)(ws + OFF_LAB);

  // zero vmask+hist+cnts+state in one async memset (contiguous region)
  hipMemsetAsync(ws + OFF_VMASK, 0, ZERO_BYTES, stream);
  k_score<<<1024, 256, 0, stream>>>(cls, keys, labs, hist);
  k_hist1<<<1024, 256, 0, stream>>>(keys, hist, hist + 256);
  k_compact_hist2<<<1024, 256, 0, stream>>>(keys, hist, hist + 256, hist + 512, cand, cntc);
  k_pivot<<<1, 1024, 0, stream>>>(cand, cntc, hist, hist + 256, hist + 512, st);
  k_select<<<NSEG, 256, 0, stream>>>(cand, cntc, st, sel, cnts3);
  k_gather<<<4, 1024, 0, stream>>>(sel, cnts3, boxes, labs, x1a, y1a, x2a, y2a,
                                   vala, laba, skeys, vmask);
  k_pairs<<<dim3(64, 64), 64, 0, stream>>>(x1a, y1a, x2a, y2a, skeys, pcnt, pairs);
  k_fix<<<1, 1024, 0, stream>>>(pcnt, pairs, vmask, skeys, x1a, y1a, x2a, y2a,
                                vala, laba, out);
}